// Round 8
// baseline (118.375 us; speedup 1.0000x reference)
//
#include <hip/hip_runtime.h>

// ---------------------------------------------------------------------------
// AI4Urban one-timestep NS solver on 64x128x256, f32.  Round 8:
//  R7 + z-coarsening (2 z-planes per thread) on k_predict/k_correct/k_final:
//  center rows of each plane serve as the other plane's z-neighbor (-20% row
//  loads, halved x-halo scalars).  Phase-sequenced A-then-B to limit VGPR.
//  Coarse/MG kernels unchanged.  10 dispatches.
// ---------------------------------------------------------------------------

constexpr int NZ = 64, NY = 128, NX = 256;
constexpr int NTOT = NZ * NY * NX;
constexpr float DT  = 0.01f;
constexpr float RDT = 100.0f;          // 1/DT
constexpr float RE  = 0.001f;
constexpr float UBC = -1.0f;
constexpr float SIXTH = 1.0f / 6.0f;
constexpr float IDIAG = -1.0f / 6.0f;  // 1/DIAG, DIAG=-6

__device__ __forceinline__ float frcp(float x) { return __builtin_amdgcn_rcpf(x); }

__device__ __forceinline__ int idx3(int z, int y, int x) {
    return (z * NY + y) * NX + x;
}

union F4 { float4 v; float f[4]; };
struct Row3 { float u[4], v[4], w[4]; };

__device__ __forceinline__ float4 ld4(const float* __restrict__ f, int z, int y, int x0) {
    return *reinterpret_cast<const float4*>(&f[idx3(z, y, x0)]);
}
__device__ __forceinline__ void st4(float* __restrict__ f, int c, const F4& a) {
    *reinterpret_cast<float4*>(&f[c]) = a.v;
}

__device__ __forceinline__ void zero4(float o[4]) {
    #pragma unroll
    for (int i = 0; i < 4; i++) o[i] = 0.f;
}

__device__ __forceinline__ void row0(const float* __restrict__ f, int z, int y, int x0,
                                     bool ok, float o[4]) {
    if (ok) { F4 a; a.v = ld4(f, z, y, x0);
        #pragma unroll
        for (int i = 0; i < 4; i++) o[i] = a.f[i];
    } else {
        zero4(o);
    }
}
// scaled row triple (solid_body), zero OOB
__device__ __forceinline__ void row3s(const float* __restrict__ u, const float* __restrict__ v,
                                      const float* __restrict__ w, const float* __restrict__ sg,
                                      int z, int y, int x0, bool ok, Row3& r) {
    if (ok) {
        F4 a, b, c, s;
        a.v = ld4(u, z, y, x0); b.v = ld4(v, z, y, x0);
        c.v = ld4(w, z, y, x0); s.v = ld4(sg, z, y, x0);
        #pragma unroll
        for (int i = 0; i < 4; i++) {
            float iv = frcp(1.f + DT * s.f[i]);
            r.u[i] = a.f[i] * iv; r.v[i] = b.f[i] * iv; r.w[i] = c.f[i] * iv;
        }
    } else {
        zero4(r.u); zero4(r.v); zero4(r.w);
    }
}
// raw row triple (zero BC)
__device__ __forceinline__ void row3z(const float* __restrict__ a, const float* __restrict__ b,
                                      const float* __restrict__ c,
                                      int z, int y, int x0, bool ok, Row3& r) {
    if (ok) {
        F4 x, yv, zv;
        x.v = ld4(a, z, y, x0); yv.v = ld4(b, z, y, x0); zv.v = ld4(c, z, y, x0);
        #pragma unroll
        for (int i = 0; i < 4; i++) { r.u[i] = x.f[i]; r.v[i] = yv.f[i]; r.w[i] = zv.f[i]; }
    } else {
        zero4(r.u); zero4(r.v); zero4(r.w);
    }
}

// XCD-aware decode for z-coarsened fine kernels: 1024 blocks, block (64,4).
// XCD k owns ztile in [4k,4k+4) (z-slab of 8).
__device__ __forceinline__ void decode_fc(int d, int& y, int& zA) {
    int k = d & 7, j = d >> 3;           // j in [0,128)
    int zt = 4 * k + (j >> 5);           // [0,32)
    y = (j & 31) * 4 + threadIdx.y;
    zA = zt * 2;
}
// 1024 blocks, block (64,4,2): XCD k owns ztile in [4k,4k+4).
__device__ __forceinline__ void decode_f2(int d, int& y, int& z, int& ytile, int& ztile) {
    int k = d & 7, j = d >> 3;
    ztile = 4 * k + (j >> 5);
    ytile = j & 31;
    z = ztile * 2 + threadIdx.z;
    y = ytile * 4 + threadIdx.y;
}

// predictor math for one plane (all inputs preloaded/scaled)
__device__ __forceinline__ void predict_plane(
    const float uc[4], const float vc[4], const float wc[4], const float inv[4],
    const Row3& Ym, const Row3& Yp, const Row3& Zm, const Row3& Zp,
    float uxmS, float vxmS, float wxmS, float uxpS, float vxpS, float wxpS,
    const F4& pc, const F4& pym, const F4& pyp, const F4& pzm, const F4& pzp,
    float pxmS, float pxpS, F4& obu, F4& obv, F4& obw) {
    #pragma unroll
    for (int i = 0; i < 4; i++) {
        float uxm = i ? uc[i - 1] : uxmS, uxp = (i < 3) ? uc[i + 1] : uxpS;
        float vxm = i ? vc[i - 1] : vxmS, vxp = (i < 3) ? vc[i + 1] : vxpS;
        float wxm = i ? wc[i - 1] : wxmS, wxp = (i < 3) ? wc[i + 1] : wxpS;
        float pxm = i ? pc.f[i - 1] : pxmS, pxp = (i < 3) ? pc.f[i + 1] : pxpS;
        float dpx = 0.5f * (pxp - pxm);
        float dpy = 0.5f * (pyp.f[i] - pym.f[i]);
        float dpz = 0.5f * (pzp.f[i] - pzm.f[i]);
        float lap_u = uxm + uxp + Ym.u[i] + Yp.u[i] + Zm.u[i] + Zp.u[i] - 6.f * uc[i];
        float lap_v = vxm + vxp + Ym.v[i] + Yp.v[i] + Zm.v[i] + Zp.v[i] - 6.f * vc[i];
        float lap_w = wxm + wxp + Ym.w[i] + Yp.w[i] + Zm.w[i] + Zp.w[i] - 6.f * wc[i];
        float bun = uc[i] + 0.5f * (RE * lap_u * DT
                    - uc[i] * (0.5f * (uxp - uxm)) * DT
                    - vc[i] * (0.5f * (Yp.u[i] - Ym.u[i])) * DT
                    - wc[i] * (0.5f * (Zp.u[i] - Zm.u[i])) * DT) - dpx * DT;
        float bvn = vc[i] + 0.5f * (RE * lap_v * DT
                    - uc[i] * (0.5f * (vxp - vxm)) * DT
                    - vc[i] * (0.5f * (Yp.v[i] - Ym.v[i])) * DT
                    - wc[i] * (0.5f * (Zp.v[i] - Zm.v[i])) * DT) - dpy * DT;
        float bwn = wc[i] + 0.5f * (RE * lap_w * DT
                    - uc[i] * (0.5f * (wxp - wxm)) * DT
                    - vc[i] * (0.5f * (Yp.w[i] - Ym.w[i])) * DT
                    - wc[i] * (0.5f * (Zp.w[i] - Zm.w[i])) * DT) - dpz * DT;
        obu.f[i] = bun * inv[i];
        obv.f[i] = bvn * inv[i];
        obw.f[i] = bwn * inv[i];
    }
}

// corrector math for one plane
__device__ __forceinline__ void correct_plane(
    const F4& u4, const F4& v4, const F4& w4, const F4& sc,
    const F4& bc_u, const F4& bc_v, const F4& bc_w,
    const Row3& Ym, const Row3& Yp, const Row3& Zm, const Row3& Zp,
    float uxmS, float vxmS, float wxmS, float uxpS, float vxpS, float wxpS,
    const F4& pc, const F4& pym, const F4& pyp, const F4& pzm, const F4& pzp,
    float pxmS, float pxpS, F4& ou, F4& ov, F4& ow) {
    #pragma unroll
    for (int i = 0; i < 4; i++) {
        float inv = frcp(1.f + DT * sc.f[i]);
        float u1c = u4.f[i] * inv, v1c = v4.f[i] * inv, w1c = w4.f[i] * inv;
        float uxm = i ? bc_u.f[i - 1] : uxmS, uxp = (i < 3) ? bc_u.f[i + 1] : uxpS;
        float vxm = i ? bc_v.f[i - 1] : vxmS, vxp = (i < 3) ? bc_v.f[i + 1] : vxpS;
        float wxm = i ? bc_w.f[i - 1] : wxmS, wxp = (i < 3) ? bc_w.f[i + 1] : wxpS;
        float pxm = i ? pc.f[i - 1] : pxmS, pxp = (i < 3) ? pc.f[i + 1] : pxpS;
        float dpx = 0.5f * (pxp - pxm);
        float dpy = 0.5f * (pyp.f[i] - pym.f[i]);
        float dpz = 0.5f * (pzp.f[i] - pzm.f[i]);
        float lap_u = uxm + uxp + Ym.u[i] + Yp.u[i] + Zm.u[i] + Zp.u[i] - 6.f * bc_u.f[i];
        float lap_v = vxm + vxp + Ym.v[i] + Yp.v[i] + Zm.v[i] + Zp.v[i] - 6.f * bc_v.f[i];
        float lap_w = wxm + wxp + Ym.w[i] + Yp.w[i] + Zm.w[i] + Zp.w[i] - 6.f * bc_w.f[i];
        float un = u1c + RE * lap_u * DT
                   - bc_u.f[i] * (0.5f * (uxp - uxm)) * DT
                   - bc_v.f[i] * (0.5f * (Yp.u[i] - Ym.u[i])) * DT
                   - bc_w.f[i] * (0.5f * (Zp.u[i] - Zm.u[i])) * DT - dpx * DT;
        float vn = v1c + RE * lap_v * DT
                   - bc_u.f[i] * (0.5f * (vxp - vxm)) * DT
                   - bc_v.f[i] * (0.5f * (Yp.v[i] - Ym.v[i])) * DT
                   - bc_w.f[i] * (0.5f * (Zp.v[i] - Zm.v[i])) * DT - dpy * DT;
        float wn = w1c + RE * lap_w * DT
                   - bc_u.f[i] * (0.5f * (wxp - wxm)) * DT
                   - bc_v.f[i] * (0.5f * (Yp.w[i] - Ym.w[i])) * DT
                   - bc_w.f[i] * (0.5f * (Zp.w[i] - Zm.w[i])) * DT - dpz * DT;
        ou.f[i] = un * inv; ov.f[i] = vn * inv; ow.f[i] = wn * inv;
    }
}

// K1: predictor, z-coarsened (planes zA, zA+1)
__global__ __launch_bounds__(256) void k_predict(
    const float* __restrict__ u, const float* __restrict__ v, const float* __restrict__ w,
    const float* __restrict__ p, const float* __restrict__ sg,
    float* __restrict__ bu, float* __restrict__ bv, float* __restrict__ bw) {
    int tx = threadIdx.x, y, zA;
    decode_fc(blockIdx.x, y, zA);
    int zB = zA + 1;
    int x0 = tx << 2, cA = idx3(zA, y, x0), cB = idx3(zB, y, x0);

    // centers (scaled) for both planes — each is the other's z-neighbor
    float invA[4], ucA[4], vcA[4], wcA[4], invB[4], ucB[4], vcB[4], wcB[4];
    {
        F4 s, a, b, c;
        s.v = ld4(sg, zA, y, x0); a.v = ld4(u, zA, y, x0);
        b.v = ld4(v, zA, y, x0);  c.v = ld4(w, zA, y, x0);
        #pragma unroll
        for (int i = 0; i < 4; i++) {
            invA[i] = frcp(1.f + DT * s.f[i]);
            ucA[i] = a.f[i] * invA[i]; vcA[i] = b.f[i] * invA[i]; wcA[i] = c.f[i] * invA[i];
        }
        s.v = ld4(sg, zB, y, x0); a.v = ld4(u, zB, y, x0);
        b.v = ld4(v, zB, y, x0);  c.v = ld4(w, zB, y, x0);
        #pragma unroll
        for (int i = 0; i < 4; i++) {
            invB[i] = frcp(1.f + DT * s.f[i]);
            ucB[i] = a.f[i] * invB[i]; vcB[i] = b.f[i] * invB[i]; wcB[i] = c.f[i] * invB[i];
        }
    }
    Row3 ZA_as_row, ZB_as_row;
    #pragma unroll
    for (int i = 0; i < 4; i++) {
        ZA_as_row.u[i] = ucA[i]; ZA_as_row.v[i] = vcA[i]; ZA_as_row.w[i] = wcA[i];
        ZB_as_row.u[i] = ucB[i]; ZB_as_row.v[i] = vcB[i]; ZB_as_row.w[i] = wcB[i];
    }
    F4 pA, pB;
    pA.v = ld4(p, zA, y, x0);
    pB.v = ld4(p, zB, y, x0);

    // ---- plane A ----
    {
        Row3 Ym, Yp, Zm;
        row3s(u, v, w, sg, zA, y - 1, x0, y > 0,      Ym);
        row3s(u, v, w, sg, zA, y + 1, x0, y < NY - 1, Yp);
        row3s(u, v, w, sg, zA - 1, y, x0, zA > 0,     Zm);
        float uxmS, vxmS, wxmS, uxpS, vxpS, wxpS;
        if (tx > 0) { float iv = frcp(1.f + DT * sg[cA - 1]);
            uxmS = u[cA - 1] * iv; vxmS = v[cA - 1] * iv; wxmS = w[cA - 1] * iv; }
        else { uxmS = UBC; vxmS = 0.f; wxmS = 0.f; }
        if (tx < 63) { float iv = frcp(1.f + DT * sg[cA + 4]);
            uxpS = u[cA + 4] * iv; vxpS = v[cA + 4] * iv; wxpS = w[cA + 4] * iv; }
        else { uxpS = vxpS = wxpS = 0.f; }
        F4 pym, pyp, pzm;
        pym.v = ld4(p, zA, y > 0 ? y - 1 : 0, x0);
        pyp.v = ld4(p, zA, y < NY - 1 ? y + 1 : y, x0);
        pzm.v = (zA > 0) ? ld4(p, zA - 1, y, x0) : pA.v;
        float pxmS = tx ? p[cA - 1] : pA.f[0];
        float pxpS = (tx < 63) ? p[cA + 4] : pA.f[3];
        F4 obu, obv, obw;
        predict_plane(ucA, vcA, wcA, invA, Ym, Yp, Zm, ZB_as_row,
                      uxmS, vxmS, wxmS, uxpS, vxpS, wxpS,
                      pA, pym, pyp, pzm, pB, pxmS, pxpS, obu, obv, obw);
        st4(bu, cA, obu); st4(bv, cA, obv); st4(bw, cA, obw);
    }
    // ---- plane B ----
    {
        Row3 Ym, Yp, Zp;
        row3s(u, v, w, sg, zB, y - 1, x0, y > 0,       Ym);
        row3s(u, v, w, sg, zB, y + 1, x0, y < NY - 1,  Yp);
        row3s(u, v, w, sg, zB + 1, y, x0, zB < NZ - 1, Zp);
        float uxmS, vxmS, wxmS, uxpS, vxpS, wxpS;
        if (tx > 0) { float iv = frcp(1.f + DT * sg[cB - 1]);
            uxmS = u[cB - 1] * iv; vxmS = v[cB - 1] * iv; wxmS = w[cB - 1] * iv; }
        else { uxmS = UBC; vxmS = 0.f; wxmS = 0.f; }
        if (tx < 63) { float iv = frcp(1.f + DT * sg[cB + 4]);
            uxpS = u[cB + 4] * iv; vxpS = v[cB + 4] * iv; wxpS = w[cB + 4] * iv; }
        else { uxpS = vxpS = wxpS = 0.f; }
        F4 pym, pyp, pzp;
        pym.v = ld4(p, zB, y > 0 ? y - 1 : 0, x0);
        pyp.v = ld4(p, zB, y < NY - 1 ? y + 1 : y, x0);
        pzp.v = (zB < NZ - 1) ? ld4(p, zB + 1, y, x0) : pB.v;
        float pxmS = tx ? p[cB - 1] : pB.f[0];
        float pxpS = (tx < 63) ? p[cB + 4] : pB.f[3];
        F4 obu, obv, obw;
        predict_plane(ucB, vcB, wcB, invB, Ym, Yp, ZA_as_row, Zp,
                      uxmS, vxmS, wxmS, uxpS, vxpS, wxpS,
                      pB, pym, pyp, pA, pzp, pxmS, pxpS, obu, obv, obw);
        st4(bu, cB, obu); st4(bv, cB, obv); st4(bw, cB, obw);
    }
}

// K2: corrector, z-coarsened
__global__ __launch_bounds__(256) void k_correct(
    const float* __restrict__ u, const float* __restrict__ v, const float* __restrict__ w,
    const float* __restrict__ sg,
    const float* __restrict__ bu, const float* __restrict__ bv, const float* __restrict__ bw,
    const float* __restrict__ p,
    float* __restrict__ u2, float* __restrict__ v2, float* __restrict__ w2) {
    int tx = threadIdx.x, y, zA;
    decode_fc(blockIdx.x, y, zA);
    int zB = zA + 1;
    int x0 = tx << 2, cA = idx3(zA, y, x0), cB = idx3(zB, y, x0);

    F4 bAu, bAv, bAw, bBu, bBv, bBw;
    bAu.v = ld4(bu, zA, y, x0); bAv.v = ld4(bv, zA, y, x0); bAw.v = ld4(bw, zA, y, x0);
    bBu.v = ld4(bu, zB, y, x0); bBv.v = ld4(bv, zB, y, x0); bBw.v = ld4(bw, zB, y, x0);
    Row3 BA_row, BB_row;
    #pragma unroll
    for (int i = 0; i < 4; i++) {
        BA_row.u[i] = bAu.f[i]; BA_row.v[i] = bAv.f[i]; BA_row.w[i] = bAw.f[i];
        BB_row.u[i] = bBu.f[i]; BB_row.v[i] = bBv.f[i]; BB_row.w[i] = bBw.f[i];
    }
    F4 pA, pB;
    pA.v = ld4(p, zA, y, x0);
    pB.v = ld4(p, zB, y, x0);

    // ---- plane A ----
    {
        Row3 Ym, Yp, Zm;
        row3z(bu, bv, bw, zA, y - 1, x0, y > 0,      Ym);
        row3z(bu, bv, bw, zA, y + 1, x0, y < NY - 1, Yp);
        row3z(bu, bv, bw, zA - 1, y, x0, zA > 0,     Zm);
        float uxmS = tx ? bu[cA - 1] : UBC,  uxpS = (tx < 63) ? bu[cA + 4] : 0.f;
        float vxmS = tx ? bv[cA - 1] : 0.f,  vxpS = (tx < 63) ? bv[cA + 4] : 0.f;
        float wxmS = tx ? bw[cA - 1] : 0.f,  wxpS = (tx < 63) ? bw[cA + 4] : 0.f;
        F4 sc, u4, v4, w4;
        sc.v = ld4(sg, zA, y, x0);
        u4.v = ld4(u, zA, y, x0); v4.v = ld4(v, zA, y, x0); w4.v = ld4(w, zA, y, x0);
        F4 pym, pyp, pzm;
        pym.v = ld4(p, zA, y > 0 ? y - 1 : 0, x0);
        pyp.v = ld4(p, zA, y < NY - 1 ? y + 1 : y, x0);
        pzm.v = (zA > 0) ? ld4(p, zA - 1, y, x0) : pA.v;
        float pxmS = tx ? p[cA - 1] : pA.f[0];
        float pxpS = (tx < 63) ? p[cA + 4] : pA.f[3];
        F4 ou, ov, ow;
        correct_plane(u4, v4, w4, sc, bAu, bAv, bAw, Ym, Yp, Zm, BB_row,
                      uxmS, vxmS, wxmS, uxpS, vxpS, wxpS,
                      pA, pym, pyp, pzm, pB, pxmS, pxpS, ou, ov, ow);
        st4(u2, cA, ou); st4(v2, cA, ov); st4(w2, cA, ow);
    }
    // ---- plane B ----
    {
        Row3 Ym, Yp, Zp;
        row3z(bu, bv, bw, zB, y - 1, x0, y > 0,       Ym);
        row3z(bu, bv, bw, zB, y + 1, x0, y < NY - 1,  Yp);
        row3z(bu, bv, bw, zB + 1, y, x0, zB < NZ - 1, Zp);
        float uxmS = tx ? bu[cB - 1] : UBC,  uxpS = (tx < 63) ? bu[cB + 4] : 0.f;
        float vxmS = tx ? bv[cB - 1] : 0.f,  vxpS = (tx < 63) ? bv[cB + 4] : 0.f;
        float wxmS = tx ? bw[cB - 1] : 0.f,  wxpS = (tx < 63) ? bw[cB + 4] : 0.f;
        F4 sc, u4, v4, w4;
        sc.v = ld4(sg, zB, y, x0);
        u4.v = ld4(u, zB, y, x0); v4.v = ld4(v, zB, y, x0); w4.v = ld4(w, zB, y, x0);
        F4 pym, pyp, pzp;
        pym.v = ld4(p, zB, y > 0 ? y - 1 : 0, x0);
        pyp.v = ld4(p, zB, y < NY - 1 ? y + 1 : y, x0);
        pzp.v = (zB < NZ - 1) ? ld4(p, zB + 1, y, x0) : pB.v;
        float pxmS = tx ? p[cB - 1] : pB.f[0];
        float pxpS = (tx < 63) ? p[cB + 4] : pB.f[3];
        F4 ou, ov, ow;
        correct_plane(u4, v4, w4, sc, bBu, bBv, bBw, Ym, Yp, BA_row, Zp,
                      uxmS, vxmS, wxmS, uxpS, vxpS, wxpS,
                      pB, pym, pyp, pA, pzp, pxmS, pxpS, ou, ov, ow);
        st4(u2, cB, ou); st4(v2, cB, ov); st4(w2, cB, ow);
    }
}

// K3: r0 = lap_ep(p) - b (b inline), plus fused level-0->1 restriction of r0.
__global__ __launch_bounds__(512) void k_divresid_r(
    const float* __restrict__ u2, const float* __restrict__ v2, const float* __restrict__ w2,
    const float* __restrict__ p, float* __restrict__ r0, float* __restrict__ r1) {
    __shared__ float lds[2][4][256];
    int tx = threadIdx.x, ty = threadIdx.y, tz = threadIdx.z;
    int y, z, ytile, ztile;
    decode_f2(blockIdx.x, y, z, ytile, ztile);
    int x0 = tx << 2, c = idx3(z, y, x0);

    F4 uc; uc.v = ld4(u2, z, y, x0);
    float uxmS = tx ? u2[c - 1] : UBC, uxpS = (tx < 63) ? u2[c + 4] : 0.f;
    float vym[4], vyp[4], wzm[4], wzp[4];
    row0(v2, z, y - 1, x0, y > 0, vym);
    row0(v2, z, y + 1, x0, y < NY - 1, vyp);
    row0(w2, z - 1, y, x0, z > 0, wzm);
    row0(w2, z + 1, y, x0, z < NZ - 1, wzp);

    F4 pc, pym, pyp, pzm, pzp;
    pc.v  = ld4(p, z, y, x0);
    pym.v = ld4(p, z, y > 0 ? y - 1 : 0, x0);
    pyp.v = ld4(p, z, y < NY - 1 ? y + 1 : y, x0);
    pzm.v = ld4(p, z > 0 ? z - 1 : 0, y, x0);
    pzp.v = ld4(p, z < NZ - 1 ? z + 1 : z, y, x0);
    float pxmS = tx ? p[c - 1] : pc.f[0];
    float pxpS = (tx < 63) ? p[c + 4] : pc.f[3];

    F4 o;
    #pragma unroll
    for (int i = 0; i < 4; i++) {
        float uxm = i ? uc.f[i - 1] : uxmS, uxp = (i < 3) ? uc.f[i + 1] : uxpS;
        float bval = -(0.5f * (uxp - uxm) + 0.5f * (vyp[i] - vym[i])
                       + 0.5f * (wzp[i] - wzm[i])) * RDT;
        float pxm = i ? pc.f[i - 1] : pxmS, pxp = (i < 3) ? pc.f[i + 1] : pxpS;
        float lap = pxm + pxp + pym.f[i] + pyp.f[i] + pzm.f[i] + pzp.f[i] - 6.f * pc.f[i];
        o.f[i] = lap - bval;
    }
    st4(r0, c, o);
    *reinterpret_cast<float4*>(&lds[tz][ty][x0]) = o.v;
    __syncthreads();
    int tid = (tz * 4 + ty) * 64 + tx;
    if (tid < 256) {
        int y1loc = tid >> 7, x1 = tid & 127;
        int xf = x1 << 1, yf = y1loc << 1;
        float s = lds[0][yf][xf]     + lds[0][yf][xf + 1]
                + lds[0][yf + 1][xf] + lds[0][yf + 1][xf + 1]
                + lds[1][yf][xf]     + lds[1][yf][xf + 1]
                + lds[1][yf + 1][xf] + lds[1][yf + 1][xf + 1];
        int y1 = ytile * 2 + y1loc, z1 = ztile;
        r1[(z1 * 64 + y1) * 128 + x1] = 0.125f * s;
    }
}

// K4: coarse down-chain r1(32,64,128) -> r2, r3, r4.  grid(4,4,4), block 512
__global__ __launch_bounds__(512) void k_down(const float* __restrict__ r1,
    float* __restrict__ r2, float* __restrict__ r3, float* __restrict__ r4) {
    __shared__ float l2[4][8][16];
    __shared__ float l3[2][4][8];
    int tid = threadIdx.x;
    int bx = blockIdx.x, by = blockIdx.y, bz = blockIdx.z;
    {
        int tx2 = tid & 15, ty2 = (tid >> 4) & 7, tz2 = tid >> 7;
        int x2 = bx * 16 + tx2, y2 = by * 8 + ty2, z2 = bz * 4 + tz2;
        const float* b0 = &r1[((size_t)(2 * z2) * 64 + 2 * y2) * 128 + 2 * x2];
        float2 a  = *reinterpret_cast<const float2*>(b0);
        float2 bq = *reinterpret_cast<const float2*>(b0 + 128);
        float2 cq = *reinterpret_cast<const float2*>(b0 + 64 * 128);
        float2 dq = *reinterpret_cast<const float2*>(b0 + 64 * 128 + 128);
        float val = 0.125f * (a.x + a.y + bq.x + bq.y + cq.x + cq.y + dq.x + dq.y);
        l2[tz2][ty2][tx2] = val;
        r2[((z2 * 32) + y2) * 64 + x2] = val;
    }
    __syncthreads();
    if (tid < 64) {
        int tx3 = tid & 7, ty3 = (tid >> 3) & 3, tz3 = tid >> 5;
        float s = l2[2*tz3][2*ty3][2*tx3]     + l2[2*tz3][2*ty3][2*tx3+1]
                + l2[2*tz3][2*ty3+1][2*tx3]   + l2[2*tz3][2*ty3+1][2*tx3+1]
                + l2[2*tz3+1][2*ty3][2*tx3]   + l2[2*tz3+1][2*ty3][2*tx3+1]
                + l2[2*tz3+1][2*ty3+1][2*tx3] + l2[2*tz3+1][2*ty3+1][2*tx3+1];
        float val = 0.125f * s;
        l3[tz3][ty3][tx3] = val;
        int x3 = bx * 8 + tx3, y3 = by * 4 + ty3, z3 = bz * 2 + tz3;
        r3[((z3 * 16) + y3) * 32 + x3] = val;
    }
    __syncthreads();
    if (tid < 8) {
        int tx4 = tid & 3, ty4 = tid >> 2;
        float s = l3[0][2*ty4][2*tx4]   + l3[0][2*ty4][2*tx4+1]
                + l3[0][2*ty4+1][2*tx4] + l3[0][2*ty4+1][2*tx4+1]
                + l3[1][2*ty4][2*tx4]   + l3[1][2*ty4][2*tx4+1]
                + l3[1][2*ty4+1][2*tx4] + l3[1][2*ty4+1][2*tx4+1];
        int x4 = bx * 4 + tx4, y4 = by * 2 + ty4, z4 = bz;
        r4[((z4 * 8) + y4) * 16 + x4] = 0.125f * s;
    }
}

__device__ __forceinline__ float a4p(const float* __restrict__ r4, int z3, int y3, int x3) {
    if ((unsigned)z3 >= 8u || (unsigned)y3 >= 16u || (unsigned)x3 >= 32u) return 0.f;
    return r4[(((z3 >> 1) * 8) + (y3 >> 1)) * 16 + (x3 >> 1)] * IDIAG;
}

// K5: fused coarse up-chain: A=r4/diag -> B(LDS) -> C+halo(LDS) -> D(level-1 out)
__global__ __launch_bounds__(512) void k_upf(const float* __restrict__ r4,
    const float* __restrict__ r3, const float* __restrict__ r2,
    const float* __restrict__ r1, float* __restrict__ D) {
    __shared__ float Bl[4][6][10];
    __shared__ float Cl[6][10][18];
    int tid = threadIdx.x;
    int bx = blockIdx.x, by = blockIdx.y, bz = blockIdx.z;
    int B0z = bz * 2 - 1, B0y = by * 4 - 1, B0x = bx * 8 - 1;
    if (tid < 240) {
        int lx = tid % 10, ly = (tid / 10) % 6, lz = tid / 60;
        int z3 = B0z + lz, y3 = B0y + ly, x3 = B0x + lx;
        float val = 0.f;
        if ((unsigned)z3 < 8u && (unsigned)y3 < 16u && (unsigned)x3 < 32u) {
            float wcn = r4[(((z3 >> 1) * 8) + (y3 >> 1)) * 16 + (x3 >> 1)] * IDIAG;
            float lap = a4p(r4, z3 - 1, y3, x3) + a4p(r4, z3 + 1, y3, x3)
                      + a4p(r4, z3, y3 - 1, x3) + a4p(r4, z3, y3 + 1, x3)
                      + a4p(r4, z3, y3, x3 - 1) + a4p(r4, z3, y3, x3 + 1) - 6.f * wcn;
            val = wcn - lap * IDIAG + r3[((z3 * 16) + y3) * 32 + x3] * IDIAG;
        }
        Bl[lz][ly][lx] = val;
    }
    __syncthreads();
    int C0z = bz * 4 - 1, C0y = by * 8 - 1, C0x = bx * 16 - 1;
    auto pB = [&](int z2, int y2, int x2) -> float {
        if ((unsigned)z2 >= 16u || (unsigned)y2 >= 32u || (unsigned)x2 >= 64u) return 0.f;
        return Bl[(z2 >> 1) - B0z][(y2 >> 1) - B0y][(x2 >> 1) - B0x];
    };
    for (int i = tid; i < 1080; i += 512) {
        int lx = i % 18, ly = (i / 18) % 10, lz = i / 180;
        int z2 = C0z + lz, y2 = C0y + ly, x2 = C0x + lx;
        float val = 0.f;
        if ((unsigned)z2 < 16u && (unsigned)y2 < 32u && (unsigned)x2 < 64u) {
            float wB = Bl[(z2 >> 1) - B0z][(y2 >> 1) - B0y][(x2 >> 1) - B0x];
            float lap = pB(z2 - 1, y2, x2) + pB(z2 + 1, y2, x2)
                      + pB(z2, y2 - 1, x2) + pB(z2, y2 + 1, x2)
                      + pB(z2, y2, x2 - 1) + pB(z2, y2, x2 + 1) - 6.f * wB;
            val = wB - lap * IDIAG + r2[((z2 * 32) + y2) * 64 + x2] * IDIAG;
        }
        Cl[lz][ly][lx] = val;
    }
    __syncthreads();
    auto pC = [&](int z1, int y1, int x1) -> float {
        if ((unsigned)z1 >= 32u || (unsigned)y1 >= 64u || (unsigned)x1 >= 128u) return 0.f;
        return Cl[(z1 >> 1) - C0z][(y1 >> 1) - C0y][(x1 >> 1) - C0x];
    };
    for (int i = tid; i < 4096; i += 512) {
        int lx = i & 31, ly = (i >> 5) & 15, lz = i >> 9;
        int z1 = bz * 8 + lz, y1 = by * 16 + ly, x1 = bx * 32 + lx;
        float wC = Cl[(z1 >> 1) - C0z][(y1 >> 1) - C0y][(x1 >> 1) - C0x];
        float lap = pC(z1 - 1, y1, x1) + pC(z1 + 1, y1, x1)
                  + pC(z1, y1 - 1, x1) + pC(z1, y1 + 1, x1)
                  + pC(z1, y1, x1 - 1) + pC(z1, y1, x1 + 1) - 6.f * wC;
        int idx = (z1 * 64 + y1) * 128 + x1;
        D[idx] = wC - lap * IDIAG + r1[idx] * IDIAG;
    }
}

// K6: iter0 p-update + iter1 residual (linearity) + fused restriction of r1res.
__global__ __launch_bounds__(512) void k_pup_resid_r(
    const float* __restrict__ pin, const float* __restrict__ D0,
    const float* __restrict__ r0, float* __restrict__ p1, float* __restrict__ r1res,
    float* __restrict__ r1) {
    __shared__ float lds[2][4][256];
    int tx = threadIdx.x, ty = threadIdx.y, tz = threadIdx.z;
    int y, z, ytile, ztile;
    decode_f2(blockIdx.x, y, z, ytile, ztile);
    int x0 = tx << 2, c = idx3(z, y, x0);
    int cz = z >> 1, cy = y >> 1, cx0 = tx << 1;

    const float* Drow = &D0[(cz * 64 + cy) * 128];
    float cr[4];
    cr[1] = Drow[cx0]; cr[2] = Drow[cx0 + 1];
    cr[0] = tx ? Drow[cx0 - 1] : cr[1];
    cr[3] = (tx < 63) ? Drow[cx0 + 2] : cr[2];
    int cym = y ? (y - 1) >> 1 : 0, cyp = (y < NY - 1) ? (y + 1) >> 1 : cy;
    int czm = z ? (z - 1) >> 1 : 0, czp = (z < NZ - 1) ? (z + 1) >> 1 : cz;
    float2 dym = *reinterpret_cast<const float2*>(&D0[(cz * 64 + cym) * 128 + cx0]);
    float2 dyp = *reinterpret_cast<const float2*>(&D0[(cz * 64 + cyp) * 128 + cx0]);
    float2 dzm = *reinterpret_cast<const float2*>(&D0[(czm * 64 + cy) * 128 + cx0]);
    float2 dzp = *reinterpret_cast<const float2*>(&D0[(czp * 64 + cy) * 128 + cx0]);

    F4 rc, rym, ryp, rzm, rzp, pin4;
    rc.v  = ld4(r0, z, y, x0);
    rym.v = ld4(r0, z, y > 0 ? y - 1 : 0, x0);
    ryp.v = ld4(r0, z, y < NY - 1 ? y + 1 : y, x0);
    rzm.v = ld4(r0, z > 0 ? z - 1 : 0, y, x0);
    rzp.v = ld4(r0, z < NZ - 1 ? z + 1 : z, y, x0);
    pin4.v = ld4(pin, z, y, x0);
    float rxmS = tx ? r0[c - 1] : rc.f[0];
    float rxpS = (tx < 63) ? r0[c + 4] : rc.f[3];

    F4 op1, ores;
    #pragma unroll
    for (int i = 0; i < 4; i++) {
        float Dc  = cr[1 + (i >> 1)];
        float Dxm = (i == 0) ? cr[0] : cr[1 + ((i - 1) >> 1)];
        float Dxp = (i == 3) ? cr[3] : cr[1 + ((i + 1) >> 1)];
        float Dym = (i < 2) ? dym.x : dym.y;
        float Dyp = (i < 2) ? dyp.x : dyp.y;
        float Dzm = (i < 2) ? dzm.x : dzm.y;
        float Dzp = (i < 2) ? dzp.x : dzp.y;
        float lapD = Dxm + Dxp + Dym + Dyp + Dzm + Dzp - 6.f * Dc;
        float rxm = i ? rc.f[i - 1] : rxmS, rxp = (i < 3) ? rc.f[i + 1] : rxpS;
        float lapR = rxm + rxp + rym.f[i] + ryp.f[i] + rzm.f[i] + rzp.f[i] - 6.f * rc.f[i];
        op1.f[i]  = pin4.f[i] - Dc + rc.f[i] * SIXTH;
        ores.f[i] = rc.f[i] - lapD + lapR * SIXTH;
    }
    st4(p1, c, op1); st4(r1res, c, ores);
    *reinterpret_cast<float4*>(&lds[tz][ty][x0]) = ores.v;
    __syncthreads();
    int tid = (tz * 4 + ty) * 64 + tx;
    if (tid < 256) {
        int y1loc = tid >> 7, x1 = tid & 127;
        int xf = x1 << 1, yf = y1loc << 1;
        float s = lds[0][yf][xf]     + lds[0][yf][xf + 1]
                + lds[0][yf + 1][xf] + lds[0][yf + 1][xf + 1]
                + lds[1][yf][xf]     + lds[1][yf][xf + 1]
                + lds[1][yf + 1][xf] + lds[1][yf + 1][xf + 1];
        int y1 = ytile * 2 + y1loc, z1 = ztile;
        r1[(z1 * 64 + y1) * 128 + x1] = 0.125f * s;
    }
}

// K7: final p-update: p2 = p1 - prol(D1) + r1res/6 ; wmg = prol(D1)
__global__ __launch_bounds__(256) void k_pup2(
    const float* __restrict__ D1, const float* __restrict__ r1res,
    float* __restrict__ pIO, float* __restrict__ wmg) {
    int tx = threadIdx.x, y = blockIdx.x * 4 + threadIdx.y, z = blockIdx.y;
    int x0 = tx << 2, c = idx3(z, y, x0);
    int cz = z >> 1, cy = y >> 1, cx0 = tx << 1;
    float2 d2 = *reinterpret_cast<const float2*>(&D1[(cz * 64 + cy) * 128 + cx0]);
    F4 rr, pp; rr.v = ld4(r1res, z, y, x0); pp.v = ld4(pIO, z, y, x0);
    F4 op, ow;
    #pragma unroll
    for (int i = 0; i < 4; i++) {
        float wv = (i < 2) ? d2.x : d2.y;
        op.f[i] = pp.f[i] - wv + rr.f[i] * SIXTH;
        ow.f[i] = wv;
    }
    st4(pIO, c, op); st4(wmg, c, ow);
}

// K8: projection + final solid_body, z-coarsened
__global__ __launch_bounds__(256) void k_final(
    const float* __restrict__ p,
    const float* __restrict__ u2, const float* __restrict__ v2, const float* __restrict__ w2,
    const float* __restrict__ sg,
    float* __restrict__ uo, float* __restrict__ vo, float* __restrict__ wo) {
    int tx = threadIdx.x, y, zA;
    decode_fc(blockIdx.x, y, zA);
    int zB = zA + 1;
    int x0 = tx << 2, cA = idx3(zA, y, x0), cB = idx3(zB, y, x0);
    F4 pA, pB;
    pA.v = ld4(p, zA, y, x0);
    pB.v = ld4(p, zB, y, x0);

    // plane A
    {
        F4 pym, pyp, pzm;
        pym.v = ld4(p, zA, y > 0 ? y - 1 : 0, x0);
        pyp.v = ld4(p, zA, y < NY - 1 ? y + 1 : y, x0);
        pzm.v = (zA > 0) ? ld4(p, zA - 1, y, x0) : pA.v;
        float pxmS = tx ? p[cA - 1] : pA.f[0];
        float pxpS = (tx < 63) ? p[cA + 4] : pA.f[3];
        F4 sc, a, b, cc;
        sc.v = ld4(sg, zA, y, x0);
        a.v = ld4(u2, zA, y, x0); b.v = ld4(v2, zA, y, x0); cc.v = ld4(w2, zA, y, x0);
        F4 ou, ov, ow;
        #pragma unroll
        for (int i = 0; i < 4; i++) {
            float pxm = i ? pA.f[i - 1] : pxmS, pxp = (i < 3) ? pA.f[i + 1] : pxpS;
            float inv = frcp(1.f + DT * sc.f[i]);
            ou.f[i] = (a.f[i]  - 0.5f * (pxp - pxm) * DT) * inv;
            ov.f[i] = (b.f[i]  - 0.5f * (pyp.f[i] - pym.f[i]) * DT) * inv;
            ow.f[i] = (cc.f[i] - 0.5f * (pB.f[i] - pzm.f[i]) * DT) * inv;
        }
        st4(uo, cA, ou); st4(vo, cA, ov); st4(wo, cA, ow);
    }
    // plane B
    {
        F4 pym, pyp, pzp;
        pym.v = ld4(p, zB, y > 0 ? y - 1 : 0, x0);
        pyp.v = ld4(p, zB, y < NY - 1 ? y + 1 : y, x0);
        pzp.v = (zB < NZ - 1) ? ld4(p, zB + 1, y, x0) : pB.v;
        float pxmS = tx ? p[cB - 1] : pB.f[0];
        float pxpS = (tx < 63) ? p[cB + 4] : pB.f[3];
        F4 sc, a, b, cc;
        sc.v = ld4(sg, zB, y, x0);
        a.v = ld4(u2, zB, y, x0); b.v = ld4(v2, zB, y, x0); cc.v = ld4(w2, zB, y, x0);
        F4 ou, ov, ow;
        #pragma unroll
        for (int i = 0; i < 4; i++) {
            float pxm = i ? pB.f[i - 1] : pxmS, pxp = (i < 3) ? pB.f[i + 1] : pxpS;
            float inv = frcp(1.f + DT * sc.f[i]);
            ou.f[i] = (a.f[i]  - 0.5f * (pxp - pxm) * DT) * inv;
            ov.f[i] = (b.f[i]  - 0.5f * (pyp.f[i] - pym.f[i]) * DT) * inv;
            ow.f[i] = (cc.f[i] - 0.5f * (pzp.f[i] - pA.f[i]) * DT) * inv;
        }
        st4(uo, cB, ou); st4(vo, cB, ov); st4(wo, cB, ow);
    }
}

extern "C" void kernel_launch(void* const* d_in, const int* in_sizes, int n_in,
                              void* d_out, int out_size, void* d_ws, size_t ws_size,
                              hipStream_t stream) {
    const float* in_u  = (const float*)d_in[0];
    const float* in_v  = (const float*)d_in[1];
    const float* in_w  = (const float*)d_in[2];
    const float* in_p  = (const float*)d_in[3];
    const float* in_sg = (const float*)d_in[4];

    float* out   = (float*)d_out;
    float* O_u   = out;                      // bu -> r1res -> u_out
    float* O_v   = out + (size_t)NTOT;       // bv -> v_out
    float* O_w   = out + (size_t)2 * NTOT;   // bw -> w_out
    float* O_p   = out + (size_t)3 * NTOT;   // p1 -> p2
    float* O_wmg = out + (size_t)4 * NTOT;   // r0 -> wmg
    float* O_r   = out + (size_t)5 * NTOT;   // final coarsest residual (512)

    float* ws  = (float*)d_ws;
    float* A0  = ws;                          // u2
    float* A1  = ws + (size_t)NTOT;           // v2
    float* A2  = ws + (size_t)2 * NTOT;       // w2
    float* r1  = ws + (size_t)3 * NTOT;       // 262144
    float* r2  = r1 + 262144;                 // 32768
    float* r3  = r2 + 32768;                  // 4096
    float* r4w = r3 + 4096;                   // 512
    float* Dw  = r4w + 512;                   // 262144

    dim3 gFC(1024);            dim3 bF(64, 4);    // z-coarsened fine kernels
    dim3 gF2(1024);            dim3 bF2(64, 4, 2);
    dim3 gP(NY / 4, NZ);
    dim3 gC(4, 4, 4);

    k_predict     <<<gFC, bF,  0, stream>>>(in_u, in_v, in_w, in_p, in_sg, O_u, O_v, O_w);
    k_correct     <<<gFC, bF,  0, stream>>>(in_u, in_v, in_w, in_sg, O_u, O_v, O_w, in_p, A0, A1, A2);
    k_divresid_r  <<<gF2, bF2, 0, stream>>>(A0, A1, A2, in_p, O_wmg /*r0*/, r1);

    // --- MG iteration 0 ---
    k_down        <<<gC, dim3(512), 0, stream>>>(r1, r2, r3, r4w);
    k_upf         <<<gC, dim3(512), 0, stream>>>(r4w, r3, r2, r1, Dw);
    k_pup_resid_r <<<gF2, bF2, 0, stream>>>(in_p, Dw, O_wmg, O_p /*p1*/, O_u /*r1res*/, r1);

    // --- MG iteration 1 ---
    k_down        <<<gC, dim3(512), 0, stream>>>(r1, r2, r3, O_r);
    k_upf         <<<gC, dim3(512), 0, stream>>>(O_r, r3, r2, r1, Dw);
    k_pup2        <<<gP, bF, 0, stream>>>(Dw, O_u /*r1res*/, O_p /*p1->p2*/, O_wmg /*wmg*/);

    k_final       <<<gFC, bF, 0, stream>>>(O_p, A0, A1, A2, in_sg, O_u, O_v, O_w);
}

// Round 9
// 102.220 us; speedup vs baseline: 1.1580x; 1.1580x over previous
//
#include <hip/hip_runtime.h>

// ---------------------------------------------------------------------------
// AI4Urban one-timestep NS solver on 64x128x256, f32.  Round 9:
//  = R7 (best, 93.4us) with k_down+k_upf fused into one k_mg kernel per MG
//  iteration via a device-scope grid barrier (64 blocks, co-resident).
//  R8 z-coarsening reverted (latency-bound regression: never trade TLP for
//  per-thread reuse on this problem).  8 dispatches + 1 memset.
// ---------------------------------------------------------------------------

constexpr int NZ = 64, NY = 128, NX = 256;
constexpr int NTOT = NZ * NY * NX;
constexpr float DT  = 0.01f;
constexpr float RDT = 100.0f;          // 1/DT
constexpr float RE  = 0.001f;
constexpr float UBC = -1.0f;
constexpr float SIXTH = 1.0f / 6.0f;
constexpr float IDIAG = -1.0f / 6.0f;  // 1/DIAG, DIAG=-6

__device__ __forceinline__ float frcp(float x) { return __builtin_amdgcn_rcpf(x); }

__device__ __forceinline__ int idx3(int z, int y, int x) {
    return (z * NY + y) * NX + x;
}

union F4 { float4 v; float f[4]; };

__device__ __forceinline__ float4 ld4(const float* __restrict__ f, int z, int y, int x0) {
    return *reinterpret_cast<const float4*>(&f[idx3(z, y, x0)]);
}
__device__ __forceinline__ void st4(float* __restrict__ f, int c, const F4& a) {
    *reinterpret_cast<float4*>(&f[c]) = a.v;
}

__device__ __forceinline__ void zero4(float o[4]) {
    #pragma unroll
    for (int i = 0; i < 4; i++) o[i] = 0.f;
}

__device__ __forceinline__ void row0(const float* __restrict__ f, int z, int y, int x0,
                                     bool ok, float o[4]) {
    if (ok) { F4 a; a.v = ld4(f, z, y, x0);
        #pragma unroll
        for (int i = 0; i < 4; i++) o[i] = a.f[i];
    } else {
        zero4(o);
    }
}
__device__ __forceinline__ void row3s(const float* __restrict__ u, const float* __restrict__ v,
                                      const float* __restrict__ w, const float* __restrict__ sg,
                                      int z, int y, int x0, bool ok,
                                      float uo[4], float vo[4], float wo[4]) {
    if (ok) {
        F4 a, b, c, s;
        a.v = ld4(u, z, y, x0); b.v = ld4(v, z, y, x0);
        c.v = ld4(w, z, y, x0); s.v = ld4(sg, z, y, x0);
        #pragma unroll
        for (int i = 0; i < 4; i++) {
            float iv = frcp(1.f + DT * s.f[i]);
            uo[i] = a.f[i] * iv; vo[i] = b.f[i] * iv; wo[i] = c.f[i] * iv;
        }
    } else {
        zero4(uo); zero4(vo); zero4(wo);
    }
}

// XCD z-slab swizzle decode: 2048 blocks, block (64,4).
__device__ __forceinline__ void decode_f(int d, int& y, int& z) {
    int k = d & 7, j = d >> 3;
    z = 8 * k + (j >> 5);
    y = (j & 31) * 4 + threadIdx.y;
}
// 1024 blocks, block (64,4,2): XCD k owns ztile in [4k,4k+4).
__device__ __forceinline__ void decode_f2(int d, int& y, int& z, int& ytile, int& ztile) {
    int k = d & 7, j = d >> 3;
    ztile = 4 * k + (j >> 5);
    ytile = j & 31;
    z = ztile * 2 + threadIdx.z;
    y = ytile * 4 + threadIdx.y;
}

// device-scope grid barrier for 64-block kernels (all co-resident)
__device__ __forceinline__ void gbar(int* cnt) {
    __syncthreads();
    if (threadIdx.x == 0) {
        __threadfence();
        __hip_atomic_fetch_add(cnt, 1, __ATOMIC_ACQ_REL, __HIP_MEMORY_SCOPE_AGENT);
        while (__hip_atomic_load(cnt, __ATOMIC_ACQUIRE, __HIP_MEMORY_SCOPE_AGENT) < 64) {}
    }
    __syncthreads();
}

// K1: predictor, solid_body fused
__global__ __launch_bounds__(256) void k_predict(
    const float* __restrict__ u, const float* __restrict__ v, const float* __restrict__ w,
    const float* __restrict__ p, const float* __restrict__ sg,
    float* __restrict__ bu, float* __restrict__ bv, float* __restrict__ bw) {
    int tx = threadIdx.x, y, z;
    decode_f(blockIdx.x, y, z);
    int x0 = tx << 2, c = idx3(z, y, x0);

    F4 sc; sc.v = ld4(sg, z, y, x0);
    F4 u4, v4, w4; u4.v = ld4(u, z, y, x0); v4.v = ld4(v, z, y, x0); w4.v = ld4(w, z, y, x0);
    float inv[4], uc[4], vc[4], wc[4];
    #pragma unroll
    for (int i = 0; i < 4; i++) {
        inv[i] = frcp(1.f + DT * sc.f[i]);
        uc[i] = u4.f[i] * inv[i]; vc[i] = v4.f[i] * inv[i]; wc[i] = w4.f[i] * inv[i];
    }
    float uym[4], vym[4], wym[4], uyp[4], vyp[4], wyp[4];
    float uzm[4], vzm[4], wzm[4], uzp[4], vzp[4], wzp[4];
    row3s(u, v, w, sg, z, y - 1, x0, y > 0,      uym, vym, wym);
    row3s(u, v, w, sg, z, y + 1, x0, y < NY - 1, uyp, vyp, wyp);
    row3s(u, v, w, sg, z - 1, y, x0, z > 0,      uzm, vzm, wzm);
    row3s(u, v, w, sg, z + 1, y, x0, z < NZ - 1, uzp, vzp, wzp);

    float uxmS, vxmS, wxmS, uxpS, vxpS, wxpS;
    if (tx > 0) { float iv = frcp(1.f + DT * sg[c - 1]);
        uxmS = u[c - 1] * iv; vxmS = v[c - 1] * iv; wxmS = w[c - 1] * iv; }
    else { uxmS = UBC; vxmS = 0.f; wxmS = 0.f; }
    if (tx < 63) { float iv = frcp(1.f + DT * sg[c + 4]);
        uxpS = u[c + 4] * iv; vxpS = v[c + 4] * iv; wxpS = w[c + 4] * iv; }
    else { uxpS = vxpS = wxpS = 0.f; }

    F4 pc, pym, pyp, pzm, pzp;
    pc.v  = ld4(p, z, y, x0);
    pym.v = ld4(p, z, y > 0 ? y - 1 : 0, x0);
    pyp.v = ld4(p, z, y < NY - 1 ? y + 1 : y, x0);
    pzm.v = ld4(p, z > 0 ? z - 1 : 0, y, x0);
    pzp.v = ld4(p, z < NZ - 1 ? z + 1 : z, y, x0);
    float pxmS = tx ? p[c - 1] : pc.f[0];
    float pxpS = (tx < 63) ? p[c + 4] : pc.f[3];

    F4 obu, obv, obw;
    #pragma unroll
    for (int i = 0; i < 4; i++) {
        float uxm = i ? uc[i - 1] : uxmS, uxp = (i < 3) ? uc[i + 1] : uxpS;
        float vxm = i ? vc[i - 1] : vxmS, vxp = (i < 3) ? vc[i + 1] : vxpS;
        float wxm = i ? wc[i - 1] : wxmS, wxp = (i < 3) ? wc[i + 1] : wxpS;
        float pxm = i ? pc.f[i - 1] : pxmS, pxp = (i < 3) ? pc.f[i + 1] : pxpS;
        float dpx = 0.5f * (pxp - pxm);
        float dpy = 0.5f * (pyp.f[i] - pym.f[i]);
        float dpz = 0.5f * (pzp.f[i] - pzm.f[i]);
        float lap_u = uxm + uxp + uym[i] + uyp[i] + uzm[i] + uzp[i] - 6.f * uc[i];
        float lap_v = vxm + vxp + vym[i] + vyp[i] + vzm[i] + vzp[i] - 6.f * vc[i];
        float lap_w = wxm + wxp + wym[i] + wyp[i] + wzm[i] + wzp[i] - 6.f * wc[i];
        float bun = uc[i] + 0.5f * (RE * lap_u * DT
                    - uc[i] * (0.5f * (uxp - uxm)) * DT
                    - vc[i] * (0.5f * (uyp[i] - uym[i])) * DT
                    - wc[i] * (0.5f * (uzp[i] - uzm[i])) * DT) - dpx * DT;
        float bvn = vc[i] + 0.5f * (RE * lap_v * DT
                    - uc[i] * (0.5f * (vxp - vxm)) * DT
                    - vc[i] * (0.5f * (vyp[i] - vym[i])) * DT
                    - wc[i] * (0.5f * (vzp[i] - vzm[i])) * DT) - dpy * DT;
        float bwn = wc[i] + 0.5f * (RE * lap_w * DT
                    - uc[i] * (0.5f * (wxp - wxm)) * DT
                    - vc[i] * (0.5f * (wyp[i] - wym[i])) * DT
                    - wc[i] * (0.5f * (wzp[i] - wzm[i])) * DT) - dpz * DT;
        obu.f[i] = bun * inv[i];
        obv.f[i] = bvn * inv[i];
        obw.f[i] = bwn * inv[i];
    }
    st4(bu, c, obu); st4(bv, c, obv); st4(bw, c, obw);
}

// K2: corrector
__global__ __launch_bounds__(256) void k_correct(
    const float* __restrict__ u, const float* __restrict__ v, const float* __restrict__ w,
    const float* __restrict__ sg,
    const float* __restrict__ bu, const float* __restrict__ bv, const float* __restrict__ bw,
    const float* __restrict__ p,
    float* __restrict__ u2, float* __restrict__ v2, float* __restrict__ w2) {
    int tx = threadIdx.x, y, z;
    decode_f(blockIdx.x, y, z);
    int x0 = tx << 2, c = idx3(z, y, x0);

    F4 sc; sc.v = ld4(sg, z, y, x0);
    F4 u4, v4, w4; u4.v = ld4(u, z, y, x0); v4.v = ld4(v, z, y, x0); w4.v = ld4(w, z, y, x0);
    F4 buc, bvc, bwc; buc.v = ld4(bu, z, y, x0); bvc.v = ld4(bv, z, y, x0); bwc.v = ld4(bw, z, y, x0);

    float uym[4], vym[4], wym[4], uyp[4], vyp[4], wyp[4];
    float uzm[4], vzm[4], wzm[4], uzp[4], vzp[4], wzp[4];
    row0(bu, z, y - 1, x0, y > 0, uym);      row0(bv, z, y - 1, x0, y > 0, vym);
    row0(bw, z, y - 1, x0, y > 0, wym);
    row0(bu, z, y + 1, x0, y < NY - 1, uyp); row0(bv, z, y + 1, x0, y < NY - 1, vyp);
    row0(bw, z, y + 1, x0, y < NY - 1, wyp);
    row0(bu, z - 1, y, x0, z > 0, uzm);      row0(bv, z - 1, y, x0, z > 0, vzm);
    row0(bw, z - 1, y, x0, z > 0, wzm);
    row0(bu, z + 1, y, x0, z < NZ - 1, uzp); row0(bv, z + 1, y, x0, z < NZ - 1, vzp);
    row0(bw, z + 1, y, x0, z < NZ - 1, wzp);

    float uxmS = tx ? bu[c - 1] : UBC,  uxpS = (tx < 63) ? bu[c + 4] : 0.f;
    float vxmS = tx ? bv[c - 1] : 0.f,  vxpS = (tx < 63) ? bv[c + 4] : 0.f;
    float wxmS = tx ? bw[c - 1] : 0.f,  wxpS = (tx < 63) ? bw[c + 4] : 0.f;

    F4 pc, pym, pyp, pzm, pzp;
    pc.v  = ld4(p, z, y, x0);
    pym.v = ld4(p, z, y > 0 ? y - 1 : 0, x0);
    pyp.v = ld4(p, z, y < NY - 1 ? y + 1 : y, x0);
    pzm.v = ld4(p, z > 0 ? z - 1 : 0, y, x0);
    pzp.v = ld4(p, z < NZ - 1 ? z + 1 : z, y, x0);
    float pxmS = tx ? p[c - 1] : pc.f[0];
    float pxpS = (tx < 63) ? p[c + 4] : pc.f[3];

    F4 ou, ov, ow;
    #pragma unroll
    for (int i = 0; i < 4; i++) {
        float inv = frcp(1.f + DT * sc.f[i]);
        float u1c = u4.f[i] * inv, v1c = v4.f[i] * inv, w1c = w4.f[i] * inv;
        float uxm = i ? buc.f[i - 1] : uxmS, uxp = (i < 3) ? buc.f[i + 1] : uxpS;
        float vxm = i ? bvc.f[i - 1] : vxmS, vxp = (i < 3) ? bvc.f[i + 1] : vxpS;
        float wxm = i ? bwc.f[i - 1] : wxmS, wxp = (i < 3) ? bwc.f[i + 1] : wxpS;
        float pxm = i ? pc.f[i - 1] : pxmS, pxp = (i < 3) ? pc.f[i + 1] : pxpS;
        float dpx = 0.5f * (pxp - pxm);
        float dpy = 0.5f * (pyp.f[i] - pym.f[i]);
        float dpz = 0.5f * (pzp.f[i] - pzm.f[i]);
        float lap_u = uxm + uxp + uym[i] + uyp[i] + uzm[i] + uzp[i] - 6.f * buc.f[i];
        float lap_v = vxm + vxp + vym[i] + vyp[i] + vzm[i] + vzp[i] - 6.f * bvc.f[i];
        float lap_w = wxm + wxp + wym[i] + wyp[i] + wzm[i] + wzp[i] - 6.f * bwc.f[i];
        float un = u1c + RE * lap_u * DT
                   - buc.f[i] * (0.5f * (uxp - uxm)) * DT
                   - bvc.f[i] * (0.5f * (uyp[i] - uym[i])) * DT
                   - bwc.f[i] * (0.5f * (uzp[i] - uzm[i])) * DT - dpx * DT;
        float vn = v1c + RE * lap_v * DT
                   - buc.f[i] * (0.5f * (vxp - vxm)) * DT
                   - bvc.f[i] * (0.5f * (vyp[i] - vym[i])) * DT
                   - bwc.f[i] * (0.5f * (vzp[i] - vzm[i])) * DT - dpy * DT;
        float wn = w1c + RE * lap_w * DT
                   - buc.f[i] * (0.5f * (wxp - wxm)) * DT
                   - bvc.f[i] * (0.5f * (wyp[i] - wym[i])) * DT
                   - bwc.f[i] * (0.5f * (wzp[i] - wzm[i])) * DT - dpz * DT;
        ou.f[i] = un * inv; ov.f[i] = vn * inv; ow.f[i] = wn * inv;
    }
    st4(u2, c, ou); st4(v2, c, ov); st4(w2, c, ow);
}

// K3: r0 = lap_ep(p) - b (b inline), plus fused level-0->1 restriction of r0.
__global__ __launch_bounds__(512) void k_divresid_r(
    const float* __restrict__ u2, const float* __restrict__ v2, const float* __restrict__ w2,
    const float* __restrict__ p, float* __restrict__ r0, float* __restrict__ r1) {
    __shared__ float lds[2][4][256];
    int tx = threadIdx.x, ty = threadIdx.y, tz = threadIdx.z;
    int y, z, ytile, ztile;
    decode_f2(blockIdx.x, y, z, ytile, ztile);
    int x0 = tx << 2, c = idx3(z, y, x0);

    F4 uc; uc.v = ld4(u2, z, y, x0);
    float uxmS = tx ? u2[c - 1] : UBC, uxpS = (tx < 63) ? u2[c + 4] : 0.f;
    float vym[4], vyp[4], wzm[4], wzp[4];
    row0(v2, z, y - 1, x0, y > 0, vym);
    row0(v2, z, y + 1, x0, y < NY - 1, vyp);
    row0(w2, z - 1, y, x0, z > 0, wzm);
    row0(w2, z + 1, y, x0, z < NZ - 1, wzp);

    F4 pc, pym, pyp, pzm, pzp;
    pc.v  = ld4(p, z, y, x0);
    pym.v = ld4(p, z, y > 0 ? y - 1 : 0, x0);
    pyp.v = ld4(p, z, y < NY - 1 ? y + 1 : y, x0);
    pzm.v = ld4(p, z > 0 ? z - 1 : 0, y, x0);
    pzp.v = ld4(p, z < NZ - 1 ? z + 1 : z, y, x0);
    float pxmS = tx ? p[c - 1] : pc.f[0];
    float pxpS = (tx < 63) ? p[c + 4] : pc.f[3];

    F4 o;
    #pragma unroll
    for (int i = 0; i < 4; i++) {
        float uxm = i ? uc.f[i - 1] : uxmS, uxp = (i < 3) ? uc.f[i + 1] : uxpS;
        float bval = -(0.5f * (uxp - uxm) + 0.5f * (vyp[i] - vym[i])
                       + 0.5f * (wzp[i] - wzm[i])) * RDT;
        float pxm = i ? pc.f[i - 1] : pxmS, pxp = (i < 3) ? pc.f[i + 1] : pxpS;
        float lap = pxm + pxp + pym.f[i] + pyp.f[i] + pzm.f[i] + pzp.f[i] - 6.f * pc.f[i];
        o.f[i] = lap - bval;
    }
    st4(r0, c, o);
    *reinterpret_cast<float4*>(&lds[tz][ty][x0]) = o.v;
    __syncthreads();
    int tid = (tz * 4 + ty) * 64 + tx;
    if (tid < 256) {
        int y1loc = tid >> 7, x1 = tid & 127;
        int xf = x1 << 1, yf = y1loc << 1;
        float s = lds[0][yf][xf]     + lds[0][yf][xf + 1]
                + lds[0][yf + 1][xf] + lds[0][yf + 1][xf + 1]
                + lds[1][yf][xf]     + lds[1][yf][xf + 1]
                + lds[1][yf + 1][xf] + lds[1][yf + 1][xf + 1];
        int y1 = ytile * 2 + y1loc, z1 = ztile;
        r1[(z1 * 64 + y1) * 128 + x1] = 0.125f * s;
    }
}

__device__ __forceinline__ float a4p(const float* __restrict__ r4, int z3, int y3, int x3) {
    if ((unsigned)z3 >= 8u || (unsigned)y3 >= 16u || (unsigned)x3 >= 32u) return 0.f;
    return r4[(((z3 >> 1) * 8) + (y3 >> 1)) * 16 + (x3 >> 1)] * IDIAG;
}

// K4: fused MG coarse chain: down (r1->r2,r3,r4) | grid barrier | up (B,C,D).
// grid(4,4,4), block 512, all 64 blocks co-resident.
__global__ __launch_bounds__(512) void k_mg(const float* __restrict__ r1,
    float* __restrict__ r2, float* __restrict__ r3, float* __restrict__ r4,
    float* __restrict__ D, int* __restrict__ cnt) {
    __shared__ float l2[4][8][16];
    __shared__ float l3[2][4][8];
    __shared__ float Bl[4][6][10];
    __shared__ float Cl[6][10][18];
    int tid = threadIdx.x;
    int bx = blockIdx.x, by = blockIdx.y, bz = blockIdx.z;

    // ---- down phase ----
    {
        int tx2 = tid & 15, ty2 = (tid >> 4) & 7, tz2 = tid >> 7;
        int x2 = bx * 16 + tx2, y2 = by * 8 + ty2, z2 = bz * 4 + tz2;
        const float* b0 = &r1[((size_t)(2 * z2) * 64 + 2 * y2) * 128 + 2 * x2];
        float2 a  = *reinterpret_cast<const float2*>(b0);
        float2 bq = *reinterpret_cast<const float2*>(b0 + 128);
        float2 cq = *reinterpret_cast<const float2*>(b0 + 64 * 128);
        float2 dq = *reinterpret_cast<const float2*>(b0 + 64 * 128 + 128);
        float val = 0.125f * (a.x + a.y + bq.x + bq.y + cq.x + cq.y + dq.x + dq.y);
        l2[tz2][ty2][tx2] = val;
        r2[((z2 * 32) + y2) * 64 + x2] = val;
    }
    __syncthreads();
    if (tid < 64) {
        int tx3 = tid & 7, ty3 = (tid >> 3) & 3, tz3 = tid >> 5;
        float s = l2[2*tz3][2*ty3][2*tx3]     + l2[2*tz3][2*ty3][2*tx3+1]
                + l2[2*tz3][2*ty3+1][2*tx3]   + l2[2*tz3][2*ty3+1][2*tx3+1]
                + l2[2*tz3+1][2*ty3][2*tx3]   + l2[2*tz3+1][2*ty3][2*tx3+1]
                + l2[2*tz3+1][2*ty3+1][2*tx3] + l2[2*tz3+1][2*ty3+1][2*tx3+1];
        float val = 0.125f * s;
        l3[tz3][ty3][tx3] = val;
        int x3 = bx * 8 + tx3, y3 = by * 4 + ty3, z3 = bz * 2 + tz3;
        r3[((z3 * 16) + y3) * 32 + x3] = val;
    }
    __syncthreads();
    if (tid < 8) {
        int tx4 = tid & 3, ty4 = tid >> 2;
        float s = l3[0][2*ty4][2*tx4]   + l3[0][2*ty4][2*tx4+1]
                + l3[0][2*ty4+1][2*tx4] + l3[0][2*ty4+1][2*tx4+1]
                + l3[1][2*ty4][2*tx4]   + l3[1][2*ty4][2*tx4+1]
                + l3[1][2*ty4+1][2*tx4] + l3[1][2*ty4+1][2*tx4+1];
        int x4 = bx * 4 + tx4, y4 = by * 2 + ty4, z4 = bz;
        r4[((z4 * 8) + y4) * 16 + x4] = 0.125f * s;
    }

    // ---- all blocks' r2/r3/r4 visible ----
    gbar(cnt);

    // ---- up phase ----
    int B0z = bz * 2 - 1, B0y = by * 4 - 1, B0x = bx * 8 - 1;
    if (tid < 240) {
        int lx = tid % 10, ly = (tid / 10) % 6, lz = tid / 60;
        int z3 = B0z + lz, y3 = B0y + ly, x3 = B0x + lx;
        float val = 0.f;
        if ((unsigned)z3 < 8u && (unsigned)y3 < 16u && (unsigned)x3 < 32u) {
            float wcn = r4[(((z3 >> 1) * 8) + (y3 >> 1)) * 16 + (x3 >> 1)] * IDIAG;
            float lap = a4p(r4, z3 - 1, y3, x3) + a4p(r4, z3 + 1, y3, x3)
                      + a4p(r4, z3, y3 - 1, x3) + a4p(r4, z3, y3 + 1, x3)
                      + a4p(r4, z3, y3, x3 - 1) + a4p(r4, z3, y3, x3 + 1) - 6.f * wcn;
            val = wcn - lap * IDIAG + r3[((z3 * 16) + y3) * 32 + x3] * IDIAG;
        }
        Bl[lz][ly][lx] = val;
    }
    __syncthreads();
    int C0z = bz * 4 - 1, C0y = by * 8 - 1, C0x = bx * 16 - 1;
    auto pB = [&](int z2, int y2, int x2) -> float {
        if ((unsigned)z2 >= 16u || (unsigned)y2 >= 32u || (unsigned)x2 >= 64u) return 0.f;
        return Bl[(z2 >> 1) - B0z][(y2 >> 1) - B0y][(x2 >> 1) - B0x];
    };
    for (int i = tid; i < 1080; i += 512) {
        int lx = i % 18, ly = (i / 18) % 10, lz = i / 180;
        int z2 = C0z + lz, y2 = C0y + ly, x2 = C0x + lx;
        float val = 0.f;
        if ((unsigned)z2 < 16u && (unsigned)y2 < 32u && (unsigned)x2 < 64u) {
            float wB = Bl[(z2 >> 1) - B0z][(y2 >> 1) - B0y][(x2 >> 1) - B0x];
            float lap = pB(z2 - 1, y2, x2) + pB(z2 + 1, y2, x2)
                      + pB(z2, y2 - 1, x2) + pB(z2, y2 + 1, x2)
                      + pB(z2, y2, x2 - 1) + pB(z2, y2, x2 + 1) - 6.f * wB;
            val = wB - lap * IDIAG + r2[((z2 * 32) + y2) * 64 + x2] * IDIAG;
        }
        Cl[lz][ly][lx] = val;
    }
    __syncthreads();
    auto pC = [&](int z1, int y1, int x1) -> float {
        if ((unsigned)z1 >= 32u || (unsigned)y1 >= 64u || (unsigned)x1 >= 128u) return 0.f;
        return Cl[(z1 >> 1) - C0z][(y1 >> 1) - C0y][(x1 >> 1) - C0x];
    };
    for (int i = tid; i < 4096; i += 512) {
        int lx = i & 31, ly = (i >> 5) & 15, lz = i >> 9;
        int z1 = bz * 8 + lz, y1 = by * 16 + ly, x1 = bx * 32 + lx;
        float wC = Cl[(z1 >> 1) - C0z][(y1 >> 1) - C0y][(x1 >> 1) - C0x];
        float lap = pC(z1 - 1, y1, x1) + pC(z1 + 1, y1, x1)
                  + pC(z1, y1 - 1, x1) + pC(z1, y1 + 1, x1)
                  + pC(z1, y1, x1 - 1) + pC(z1, y1, x1 + 1) - 6.f * wC;
        int idx = (z1 * 64 + y1) * 128 + x1;
        D[idx] = wC - lap * IDIAG + r1[idx] * IDIAG;
    }
}

// K5: iter0 p-update + iter1 residual (linearity) + fused restriction of r1res.
__global__ __launch_bounds__(512) void k_pup_resid_r(
    const float* __restrict__ pin, const float* __restrict__ D0,
    const float* __restrict__ r0, float* __restrict__ p1, float* __restrict__ r1res,
    float* __restrict__ r1) {
    __shared__ float lds[2][4][256];
    int tx = threadIdx.x, ty = threadIdx.y, tz = threadIdx.z;
    int y, z, ytile, ztile;
    decode_f2(blockIdx.x, y, z, ytile, ztile);
    int x0 = tx << 2, c = idx3(z, y, x0);
    int cz = z >> 1, cy = y >> 1, cx0 = tx << 1;

    const float* Drow = &D0[(cz * 64 + cy) * 128];
    float cr[4];
    cr[1] = Drow[cx0]; cr[2] = Drow[cx0 + 1];
    cr[0] = tx ? Drow[cx0 - 1] : cr[1];
    cr[3] = (tx < 63) ? Drow[cx0 + 2] : cr[2];
    int cym = y ? (y - 1) >> 1 : 0, cyp = (y < NY - 1) ? (y + 1) >> 1 : cy;
    int czm = z ? (z - 1) >> 1 : 0, czp = (z < NZ - 1) ? (z + 1) >> 1 : cz;
    float2 dym = *reinterpret_cast<const float2*>(&D0[(cz * 64 + cym) * 128 + cx0]);
    float2 dyp = *reinterpret_cast<const float2*>(&D0[(cz * 64 + cyp) * 128 + cx0]);
    float2 dzm = *reinterpret_cast<const float2*>(&D0[(czm * 64 + cy) * 128 + cx0]);
    float2 dzp = *reinterpret_cast<const float2*>(&D0[(czp * 64 + cy) * 128 + cx0]);

    F4 rc, rym, ryp, rzm, rzp, pin4;
    rc.v  = ld4(r0, z, y, x0);
    rym.v = ld4(r0, z, y > 0 ? y - 1 : 0, x0);
    ryp.v = ld4(r0, z, y < NY - 1 ? y + 1 : y, x0);
    rzm.v = ld4(r0, z > 0 ? z - 1 : 0, y, x0);
    rzp.v = ld4(r0, z < NZ - 1 ? z + 1 : z, y, x0);
    pin4.v = ld4(pin, z, y, x0);
    float rxmS = tx ? r0[c - 1] : rc.f[0];
    float rxpS = (tx < 63) ? r0[c + 4] : rc.f[3];

    F4 op1, ores;
    #pragma unroll
    for (int i = 0; i < 4; i++) {
        float Dc  = cr[1 + (i >> 1)];
        float Dxm = (i == 0) ? cr[0] : cr[1 + ((i - 1) >> 1)];
        float Dxp = (i == 3) ? cr[3] : cr[1 + ((i + 1) >> 1)];
        float Dym = (i < 2) ? dym.x : dym.y;
        float Dyp = (i < 2) ? dyp.x : dyp.y;
        float Dzm = (i < 2) ? dzm.x : dzm.y;
        float Dzp = (i < 2) ? dzp.x : dzp.y;
        float lapD = Dxm + Dxp + Dym + Dyp + Dzm + Dzp - 6.f * Dc;
        float rxm = i ? rc.f[i - 1] : rxmS, rxp = (i < 3) ? rc.f[i + 1] : rxpS;
        float lapR = rxm + rxp + rym.f[i] + ryp.f[i] + rzm.f[i] + rzp.f[i] - 6.f * rc.f[i];
        op1.f[i]  = pin4.f[i] - Dc + rc.f[i] * SIXTH;
        ores.f[i] = rc.f[i] - lapD + lapR * SIXTH;
    }
    st4(p1, c, op1); st4(r1res, c, ores);
    *reinterpret_cast<float4*>(&lds[tz][ty][x0]) = ores.v;
    __syncthreads();
    int tid = (tz * 4 + ty) * 64 + tx;
    if (tid < 256) {
        int y1loc = tid >> 7, x1 = tid & 127;
        int xf = x1 << 1, yf = y1loc << 1;
        float s = lds[0][yf][xf]     + lds[0][yf][xf + 1]
                + lds[0][yf + 1][xf] + lds[0][yf + 1][xf + 1]
                + lds[1][yf][xf]     + lds[1][yf][xf + 1]
                + lds[1][yf + 1][xf] + lds[1][yf + 1][xf + 1];
        int y1 = ytile * 2 + y1loc, z1 = ztile;
        r1[(z1 * 64 + y1) * 128 + x1] = 0.125f * s;
    }
}

// K6: final p-update: p2 = p1 - prol(D1) + r1res/6 ; wmg = prol(D1)
__global__ __launch_bounds__(256) void k_pup2(
    const float* __restrict__ D1, const float* __restrict__ r1res,
    float* __restrict__ pIO, float* __restrict__ wmg) {
    int tx = threadIdx.x, y = blockIdx.x * 4 + threadIdx.y, z = blockIdx.y;
    int x0 = tx << 2, c = idx3(z, y, x0);
    int cz = z >> 1, cy = y >> 1, cx0 = tx << 1;
    float2 d2 = *reinterpret_cast<const float2*>(&D1[(cz * 64 + cy) * 128 + cx0]);
    F4 rr, pp; rr.v = ld4(r1res, z, y, x0); pp.v = ld4(pIO, z, y, x0);
    F4 op, ow;
    #pragma unroll
    for (int i = 0; i < 4; i++) {
        float wv = (i < 2) ? d2.x : d2.y;
        op.f[i] = pp.f[i] - wv + rr.f[i] * SIXTH;
        ow.f[i] = wv;
    }
    st4(pIO, c, op); st4(wmg, c, ow);
}

// K7: projection + final solid_body
__global__ __launch_bounds__(256) void k_final(
    const float* __restrict__ p,
    const float* __restrict__ u2, const float* __restrict__ v2, const float* __restrict__ w2,
    const float* __restrict__ sg,
    float* __restrict__ uo, float* __restrict__ vo, float* __restrict__ wo) {
    int tx = threadIdx.x, y, z;
    decode_f(blockIdx.x, y, z);
    int x0 = tx << 2, c = idx3(z, y, x0);
    F4 pc, pym, pyp, pzm, pzp;
    pc.v  = ld4(p, z, y, x0);
    pym.v = ld4(p, z, y > 0 ? y - 1 : 0, x0);
    pyp.v = ld4(p, z, y < NY - 1 ? y + 1 : y, x0);
    pzm.v = ld4(p, z > 0 ? z - 1 : 0, y, x0);
    pzp.v = ld4(p, z < NZ - 1 ? z + 1 : z, y, x0);
    float pxmS = tx ? p[c - 1] : pc.f[0];
    float pxpS = (tx < 63) ? p[c + 4] : pc.f[3];
    F4 sc; sc.v = ld4(sg, z, y, x0);
    F4 a, b, cc; a.v = ld4(u2, z, y, x0); b.v = ld4(v2, z, y, x0); cc.v = ld4(w2, z, y, x0);
    F4 ou, ov, ow;
    #pragma unroll
    for (int i = 0; i < 4; i++) {
        float pxm = i ? pc.f[i - 1] : pxmS, pxp = (i < 3) ? pc.f[i + 1] : pxpS;
        float inv = frcp(1.f + DT * sc.f[i]);
        ou.f[i] = (a.f[i]  - 0.5f * (pxp - pxm) * DT) * inv;
        ov.f[i] = (b.f[i]  - 0.5f * (pyp.f[i] - pym.f[i]) * DT) * inv;
        ow.f[i] = (cc.f[i] - 0.5f * (pzp.f[i] - pzm.f[i]) * DT) * inv;
    }
    st4(uo, c, ou); st4(vo, c, ov); st4(wo, c, ow);
}

extern "C" void kernel_launch(void* const* d_in, const int* in_sizes, int n_in,
                              void* d_out, int out_size, void* d_ws, size_t ws_size,
                              hipStream_t stream) {
    const float* in_u  = (const float*)d_in[0];
    const float* in_v  = (const float*)d_in[1];
    const float* in_w  = (const float*)d_in[2];
    const float* in_p  = (const float*)d_in[3];
    const float* in_sg = (const float*)d_in[4];

    float* out   = (float*)d_out;
    float* O_u   = out;                      // bu -> r1res -> u_out
    float* O_v   = out + (size_t)NTOT;       // bv -> v_out
    float* O_w   = out + (size_t)2 * NTOT;   // bw -> w_out
    float* O_p   = out + (size_t)3 * NTOT;   // p1 -> p2
    float* O_wmg = out + (size_t)4 * NTOT;   // r0 -> wmg
    float* O_r   = out + (size_t)5 * NTOT;   // final coarsest residual (512)

    float* ws  = (float*)d_ws;
    float* A0  = ws;                          // u2
    float* A1  = ws + (size_t)NTOT;           // v2
    float* A2  = ws + (size_t)2 * NTOT;       // w2
    float* r1  = ws + (size_t)3 * NTOT;       // 262144
    float* r2  = r1 + 262144;                 // 32768
    float* r3  = r2 + 32768;                  // 4096
    float* r4w = r3 + 4096;                   // 512
    float* Dw  = r4w + 512;                   // 262144
    int*   cnts = (int*)(Dw + 262144);        // 2 barrier counters

    dim3 gF(2048);             dim3 bF(64, 4);
    dim3 gF2(1024);            dim3 bF2(64, 4, 2);
    dim3 gP(NY / 4, NZ);
    dim3 gC(4, 4, 4);

    hipMemsetAsync(cnts, 0, 2 * sizeof(int), stream);

    k_predict     <<<gF,  bF,  0, stream>>>(in_u, in_v, in_w, in_p, in_sg, O_u, O_v, O_w);
    k_correct     <<<gF,  bF,  0, stream>>>(in_u, in_v, in_w, in_sg, O_u, O_v, O_w, in_p, A0, A1, A2);
    k_divresid_r  <<<gF2, bF2, 0, stream>>>(A0, A1, A2, in_p, O_wmg /*r0*/, r1);

    // --- MG iteration 0 ---
    k_mg          <<<gC, dim3(512), 0, stream>>>(r1, r2, r3, r4w, Dw, cnts);
    k_pup_resid_r <<<gF2, bF2, 0, stream>>>(in_p, Dw, O_wmg, O_p /*p1*/, O_u /*r1res*/, r1);

    // --- MG iteration 1 ---
    k_mg          <<<gC, dim3(512), 0, stream>>>(r1, r2, r3, O_r, Dw, cnts + 1);
    k_pup2        <<<gP, bF, 0, stream>>>(Dw, O_u /*r1res*/, O_p /*p1->p2*/, O_wmg /*wmg*/);

    k_final       <<<gF, bF, 0, stream>>>(O_p, A0, A1, A2, in_sg, O_u, O_v, O_w);
}

// Round 10
// 92.020 us; speedup vs baseline: 1.2864x; 1.1108x over previous
//
#include <hip/hip_runtime.h>

// ---------------------------------------------------------------------------
// AI4Urban one-timestep NS solver on 64x128x256, f32.  Round 10:
//  = R7 (champion, 93.4us; R9 grid-barrier fusion reverted) + LDS row-sharing
//  in k_predict/k_correct/k_final: block = 4 consecutive y rows; center rows
//  stored in LDS serve as neighbors' y-rows and x-halos (~30% fewer L1/L2
//  reads, TLP unchanged).  10 dispatches.
// ---------------------------------------------------------------------------

constexpr int NZ = 64, NY = 128, NX = 256;
constexpr int NTOT = NZ * NY * NX;
constexpr float DT  = 0.01f;
constexpr float RDT = 100.0f;          // 1/DT
constexpr float RE  = 0.001f;
constexpr float UBC = -1.0f;
constexpr float SIXTH = 1.0f / 6.0f;
constexpr float IDIAG = -1.0f / 6.0f;  // 1/DIAG, DIAG=-6

__device__ __forceinline__ float frcp(float x) { return __builtin_amdgcn_rcpf(x); }

__device__ __forceinline__ int idx3(int z, int y, int x) {
    return (z * NY + y) * NX + x;
}

union F4 { float4 v; float f[4]; };

__device__ __forceinline__ float4 ld4(const float* __restrict__ f, int z, int y, int x0) {
    return *reinterpret_cast<const float4*>(&f[idx3(z, y, x0)]);
}
__device__ __forceinline__ void st4(float* __restrict__ f, int c, const F4& a) {
    *reinterpret_cast<float4*>(&f[c]) = a.v;
}
__device__ __forceinline__ float4 ldsrow(const float* r, int x0) {
    return *reinterpret_cast<const float4*>(&r[x0]);
}

__device__ __forceinline__ void zero4(float o[4]) {
    #pragma unroll
    for (int i = 0; i < 4; i++) o[i] = 0.f;
}

__device__ __forceinline__ void row0(const float* __restrict__ f, int z, int y, int x0,
                                     bool ok, float o[4]) {
    if (ok) { F4 a; a.v = ld4(f, z, y, x0);
        #pragma unroll
        for (int i = 0; i < 4; i++) o[i] = a.f[i];
    } else {
        zero4(o);
    }
}
__device__ __forceinline__ void row3s(const float* __restrict__ u, const float* __restrict__ v,
                                      const float* __restrict__ w, const float* __restrict__ sg,
                                      int z, int y, int x0, bool ok,
                                      float uo[4], float vo[4], float wo[4]) {
    if (ok) {
        F4 a, b, c, s;
        a.v = ld4(u, z, y, x0); b.v = ld4(v, z, y, x0);
        c.v = ld4(w, z, y, x0); s.v = ld4(sg, z, y, x0);
        #pragma unroll
        for (int i = 0; i < 4; i++) {
            float iv = frcp(1.f + DT * s.f[i]);
            uo[i] = a.f[i] * iv; vo[i] = b.f[i] * iv; wo[i] = c.f[i] * iv;
        }
    } else {
        zero4(uo); zero4(vo); zero4(wo);
    }
}

// XCD z-slab swizzle decode: 2048 blocks, block (64,4).
__device__ __forceinline__ void decode_f(int d, int& y, int& z) {
    int k = d & 7, j = d >> 3;
    z = 8 * k + (j >> 5);
    y = (j & 31) * 4 + threadIdx.y;
}
// 1024 blocks, block (64,4,2): XCD k owns ztile in [4k,4k+4).
__device__ __forceinline__ void decode_f2(int d, int& y, int& z, int& ytile, int& ztile) {
    int k = d & 7, j = d >> 3;
    ztile = 4 * k + (j >> 5);
    ytile = j & 31;
    z = ztile * 2 + threadIdx.z;
    y = ytile * 4 + threadIdx.y;
}

// K1: predictor, solid_body fused; LDS row-sharing across the 4-y block
__global__ __launch_bounds__(256) void k_predict(
    const float* __restrict__ u, const float* __restrict__ v, const float* __restrict__ w,
    const float* __restrict__ p, const float* __restrict__ sg,
    float* __restrict__ bu, float* __restrict__ bv, float* __restrict__ bw) {
    __shared__ __align__(16) float su[6][256], sv[6][256], sw[6][256], sp[6][256];
    int tx = threadIdx.x, ty = threadIdx.y, y, z;
    decode_f(blockIdx.x, y, z);
    int x0 = tx << 2, c = idx3(z, y, x0);

    F4 sc; sc.v = ld4(sg, z, y, x0);
    F4 u4, v4, w4; u4.v = ld4(u, z, y, x0); v4.v = ld4(v, z, y, x0); w4.v = ld4(w, z, y, x0);
    F4 pc; pc.v = ld4(p, z, y, x0);
    float inv[4], uc[4], vc[4], wc[4];
    #pragma unroll
    for (int i = 0; i < 4; i++) {
        inv[i] = frcp(1.f + DT * sc.f[i]);
        uc[i] = u4.f[i] * inv[i]; vc[i] = v4.f[i] * inv[i]; wc[i] = w4.f[i] * inv[i];
        su[ty + 1][x0 + i] = uc[i]; sv[ty + 1][x0 + i] = vc[i];
        sw[ty + 1][x0 + i] = wc[i]; sp[ty + 1][x0 + i] = pc.f[i];
    }
    if (ty == 0) {
        int ym = y - 1;
        if (ym >= 0) {
            F4 a, b, c2, s;
            a.v = ld4(u, z, ym, x0); b.v = ld4(v, z, ym, x0);
            c2.v = ld4(w, z, ym, x0); s.v = ld4(sg, z, ym, x0);
            #pragma unroll
            for (int i = 0; i < 4; i++) {
                float iv = frcp(1.f + DT * s.f[i]);
                su[0][x0 + i] = a.f[i] * iv; sv[0][x0 + i] = b.f[i] * iv;
                sw[0][x0 + i] = c2.f[i] * iv;
            }
        } else {
            #pragma unroll
            for (int i = 0; i < 4; i++) { su[0][x0+i] = 0.f; sv[0][x0+i] = 0.f; sw[0][x0+i] = 0.f; }
        }
        F4 pp; pp.v = ld4(p, z, ym >= 0 ? ym : 0, x0);
        #pragma unroll
        for (int i = 0; i < 4; i++) sp[0][x0 + i] = pp.f[i];
    } else if (ty == 3) {
        int yp = y + 1;
        if (yp < NY) {
            F4 a, b, c2, s;
            a.v = ld4(u, z, yp, x0); b.v = ld4(v, z, yp, x0);
            c2.v = ld4(w, z, yp, x0); s.v = ld4(sg, z, yp, x0);
            #pragma unroll
            for (int i = 0; i < 4; i++) {
                float iv = frcp(1.f + DT * s.f[i]);
                su[5][x0 + i] = a.f[i] * iv; sv[5][x0 + i] = b.f[i] * iv;
                sw[5][x0 + i] = c2.f[i] * iv;
            }
        } else {
            #pragma unroll
            for (int i = 0; i < 4; i++) { su[5][x0+i] = 0.f; sv[5][x0+i] = 0.f; sw[5][x0+i] = 0.f; }
        }
        F4 pp; pp.v = ld4(p, z, yp < NY ? yp : NY - 1, x0);
        #pragma unroll
        for (int i = 0; i < 4; i++) sp[5][x0 + i] = pp.f[i];
    }
    __syncthreads();

    F4 Uym, Uyp, Vym, Vyp, Wym, Wyp, Pym, Pyp;
    Uym.v = ldsrow(su[ty], x0);     Uyp.v = ldsrow(su[ty + 2], x0);
    Vym.v = ldsrow(sv[ty], x0);     Vyp.v = ldsrow(sv[ty + 2], x0);
    Wym.v = ldsrow(sw[ty], x0);     Wyp.v = ldsrow(sw[ty + 2], x0);
    Pym.v = ldsrow(sp[ty], x0);     Pyp.v = ldsrow(sp[ty + 2], x0);

    float uzm[4], vzm[4], wzm[4], uzp[4], vzp[4], wzp[4];
    row3s(u, v, w, sg, z - 1, y, x0, z > 0,      uzm, vzm, wzm);
    row3s(u, v, w, sg, z + 1, y, x0, z < NZ - 1, uzp, vzp, wzp);
    F4 pzm, pzp;
    pzm.v = ld4(p, z > 0 ? z - 1 : 0, y, x0);
    pzp.v = ld4(p, z < NZ - 1 ? z + 1 : z, y, x0);

    float uxmS = tx ? su[ty + 1][x0 - 1] : UBC;
    float vxmS = tx ? sv[ty + 1][x0 - 1] : 0.f;
    float wxmS = tx ? sw[ty + 1][x0 - 1] : 0.f;
    float uxpS = (tx < 63) ? su[ty + 1][x0 + 4] : 0.f;
    float vxpS = (tx < 63) ? sv[ty + 1][x0 + 4] : 0.f;
    float wxpS = (tx < 63) ? sw[ty + 1][x0 + 4] : 0.f;
    float pxmS = tx ? sp[ty + 1][x0 - 1] : pc.f[0];
    float pxpS = (tx < 63) ? sp[ty + 1][x0 + 4] : pc.f[3];

    F4 obu, obv, obw;
    #pragma unroll
    for (int i = 0; i < 4; i++) {
        float uxm = i ? uc[i - 1] : uxmS, uxp = (i < 3) ? uc[i + 1] : uxpS;
        float vxm = i ? vc[i - 1] : vxmS, vxp = (i < 3) ? vc[i + 1] : vxpS;
        float wxm = i ? wc[i - 1] : wxmS, wxp = (i < 3) ? wc[i + 1] : wxpS;
        float pxm = i ? pc.f[i - 1] : pxmS, pxp = (i < 3) ? pc.f[i + 1] : pxpS;
        float dpx = 0.5f * (pxp - pxm);
        float dpy = 0.5f * (Pyp.f[i] - Pym.f[i]);
        float dpz = 0.5f * (pzp.f[i] - pzm.f[i]);
        float lap_u = uxm + uxp + Uym.f[i] + Uyp.f[i] + uzm[i] + uzp[i] - 6.f * uc[i];
        float lap_v = vxm + vxp + Vym.f[i] + Vyp.f[i] + vzm[i] + vzp[i] - 6.f * vc[i];
        float lap_w = wxm + wxp + Wym.f[i] + Wyp.f[i] + wzm[i] + wzp[i] - 6.f * wc[i];
        float bun = uc[i] + 0.5f * (RE * lap_u * DT
                    - uc[i] * (0.5f * (uxp - uxm)) * DT
                    - vc[i] * (0.5f * (Uyp.f[i] - Uym.f[i])) * DT
                    - wc[i] * (0.5f * (uzp[i] - uzm[i])) * DT) - dpx * DT;
        float bvn = vc[i] + 0.5f * (RE * lap_v * DT
                    - uc[i] * (0.5f * (vxp - vxm)) * DT
                    - vc[i] * (0.5f * (Vyp.f[i] - Vym.f[i])) * DT
                    - wc[i] * (0.5f * (vzp[i] - vzm[i])) * DT) - dpy * DT;
        float bwn = wc[i] + 0.5f * (RE * lap_w * DT
                    - uc[i] * (0.5f * (wxp - wxm)) * DT
                    - vc[i] * (0.5f * (Wyp.f[i] - Wym.f[i])) * DT
                    - wc[i] * (0.5f * (wzp[i] - wzm[i])) * DT) - dpz * DT;
        obu.f[i] = bun * inv[i];
        obv.f[i] = bvn * inv[i];
        obw.f[i] = bwn * inv[i];
    }
    st4(bu, c, obu); st4(bv, c, obv); st4(bw, c, obw);
}

// K2: corrector; LDS row-sharing of bu/bv/bw and p
__global__ __launch_bounds__(256) void k_correct(
    const float* __restrict__ u, const float* __restrict__ v, const float* __restrict__ w,
    const float* __restrict__ sg,
    const float* __restrict__ bu, const float* __restrict__ bv, const float* __restrict__ bw,
    const float* __restrict__ p,
    float* __restrict__ u2, float* __restrict__ v2, float* __restrict__ w2) {
    __shared__ __align__(16) float su[6][256], sv[6][256], sw[6][256], sp[6][256];
    int tx = threadIdx.x, ty = threadIdx.y, y, z;
    decode_f(blockIdx.x, y, z);
    int x0 = tx << 2, c = idx3(z, y, x0);

    F4 sc; sc.v = ld4(sg, z, y, x0);
    F4 u4, v4, w4; u4.v = ld4(u, z, y, x0); v4.v = ld4(v, z, y, x0); w4.v = ld4(w, z, y, x0);
    F4 buc, bvc, bwc; buc.v = ld4(bu, z, y, x0); bvc.v = ld4(bv, z, y, x0); bwc.v = ld4(bw, z, y, x0);
    F4 pc; pc.v = ld4(p, z, y, x0);
    #pragma unroll
    for (int i = 0; i < 4; i++) {
        su[ty + 1][x0 + i] = buc.f[i]; sv[ty + 1][x0 + i] = bvc.f[i];
        sw[ty + 1][x0 + i] = bwc.f[i]; sp[ty + 1][x0 + i] = pc.f[i];
    }
    if (ty == 0) {
        int ym = y - 1;
        if (ym >= 0) {
            F4 a, b, c2;
            a.v = ld4(bu, z, ym, x0); b.v = ld4(bv, z, ym, x0); c2.v = ld4(bw, z, ym, x0);
            #pragma unroll
            for (int i = 0; i < 4; i++) { su[0][x0+i] = a.f[i]; sv[0][x0+i] = b.f[i]; sw[0][x0+i] = c2.f[i]; }
        } else {
            #pragma unroll
            for (int i = 0; i < 4; i++) { su[0][x0+i] = 0.f; sv[0][x0+i] = 0.f; sw[0][x0+i] = 0.f; }
        }
        F4 pp; pp.v = ld4(p, z, ym >= 0 ? ym : 0, x0);
        #pragma unroll
        for (int i = 0; i < 4; i++) sp[0][x0 + i] = pp.f[i];
    } else if (ty == 3) {
        int yp = y + 1;
        if (yp < NY) {
            F4 a, b, c2;
            a.v = ld4(bu, z, yp, x0); b.v = ld4(bv, z, yp, x0); c2.v = ld4(bw, z, yp, x0);
            #pragma unroll
            for (int i = 0; i < 4; i++) { su[5][x0+i] = a.f[i]; sv[5][x0+i] = b.f[i]; sw[5][x0+i] = c2.f[i]; }
        } else {
            #pragma unroll
            for (int i = 0; i < 4; i++) { su[5][x0+i] = 0.f; sv[5][x0+i] = 0.f; sw[5][x0+i] = 0.f; }
        }
        F4 pp; pp.v = ld4(p, z, yp < NY ? yp : NY - 1, x0);
        #pragma unroll
        for (int i = 0; i < 4; i++) sp[5][x0 + i] = pp.f[i];
    }
    __syncthreads();

    F4 Uym, Uyp, Vym, Vyp, Wym, Wyp, Pym, Pyp;
    Uym.v = ldsrow(su[ty], x0);     Uyp.v = ldsrow(su[ty + 2], x0);
    Vym.v = ldsrow(sv[ty], x0);     Vyp.v = ldsrow(sv[ty + 2], x0);
    Wym.v = ldsrow(sw[ty], x0);     Wyp.v = ldsrow(sw[ty + 2], x0);
    Pym.v = ldsrow(sp[ty], x0);     Pyp.v = ldsrow(sp[ty + 2], x0);

    float uzm[4], vzm[4], wzm[4], uzp[4], vzp[4], wzp[4];
    row0(bu, z - 1, y, x0, z > 0, uzm);      row0(bv, z - 1, y, x0, z > 0, vzm);
    row0(bw, z - 1, y, x0, z > 0, wzm);
    row0(bu, z + 1, y, x0, z < NZ - 1, uzp); row0(bv, z + 1, y, x0, z < NZ - 1, vzp);
    row0(bw, z + 1, y, x0, z < NZ - 1, wzp);
    F4 pzm, pzp;
    pzm.v = ld4(p, z > 0 ? z - 1 : 0, y, x0);
    pzp.v = ld4(p, z < NZ - 1 ? z + 1 : z, y, x0);

    float uxmS = tx ? su[ty + 1][x0 - 1] : UBC;
    float vxmS = tx ? sv[ty + 1][x0 - 1] : 0.f;
    float wxmS = tx ? sw[ty + 1][x0 - 1] : 0.f;
    float uxpS = (tx < 63) ? su[ty + 1][x0 + 4] : 0.f;
    float vxpS = (tx < 63) ? sv[ty + 1][x0 + 4] : 0.f;
    float wxpS = (tx < 63) ? sw[ty + 1][x0 + 4] : 0.f;
    float pxmS = tx ? sp[ty + 1][x0 - 1] : pc.f[0];
    float pxpS = (tx < 63) ? sp[ty + 1][x0 + 4] : pc.f[3];

    F4 ou, ov, ow;
    #pragma unroll
    for (int i = 0; i < 4; i++) {
        float inv = frcp(1.f + DT * sc.f[i]);
        float u1c = u4.f[i] * inv, v1c = v4.f[i] * inv, w1c = w4.f[i] * inv;
        float uxm = i ? buc.f[i - 1] : uxmS, uxp = (i < 3) ? buc.f[i + 1] : uxpS;
        float vxm = i ? bvc.f[i - 1] : vxmS, vxp = (i < 3) ? bvc.f[i + 1] : vxpS;
        float wxm = i ? bwc.f[i - 1] : wxmS, wxp = (i < 3) ? bwc.f[i + 1] : wxpS;
        float pxm = i ? pc.f[i - 1] : pxmS, pxp = (i < 3) ? pc.f[i + 1] : pxpS;
        float dpx = 0.5f * (pxp - pxm);
        float dpy = 0.5f * (Pyp.f[i] - Pym.f[i]);
        float dpz = 0.5f * (pzp.f[i] - pzm.f[i]);
        float lap_u = uxm + uxp + Uym.f[i] + Uyp.f[i] + uzm[i] + uzp[i] - 6.f * buc.f[i];
        float lap_v = vxm + vxp + Vym.f[i] + Vyp.f[i] + vzm[i] + vzp[i] - 6.f * bvc.f[i];
        float lap_w = wxm + wxp + Wym.f[i] + Wyp.f[i] + wzm[i] + wzp[i] - 6.f * bwc.f[i];
        float un = u1c + RE * lap_u * DT
                   - buc.f[i] * (0.5f * (uxp - uxm)) * DT
                   - bvc.f[i] * (0.5f * (Uyp.f[i] - Uym.f[i])) * DT
                   - bwc.f[i] * (0.5f * (uzp[i] - uzm[i])) * DT - dpx * DT;
        float vn = v1c + RE * lap_v * DT
                   - buc.f[i] * (0.5f * (vxp - vxm)) * DT
                   - bvc.f[i] * (0.5f * (Vyp.f[i] - Vym.f[i])) * DT
                   - bwc.f[i] * (0.5f * (vzp[i] - vzm[i])) * DT - dpy * DT;
        float wn = w1c + RE * lap_w * DT
                   - buc.f[i] * (0.5f * (wxp - wxm)) * DT
                   - bvc.f[i] * (0.5f * (Wyp.f[i] - Wym.f[i])) * DT
                   - bwc.f[i] * (0.5f * (wzp[i] - wzm[i])) * DT - dpz * DT;
        ou.f[i] = un * inv; ov.f[i] = vn * inv; ow.f[i] = wn * inv;
    }
    st4(u2, c, ou); st4(v2, c, ov); st4(w2, c, ow);
}

// K3: r0 = lap_ep(p) - b (b inline), plus fused level-0->1 restriction of r0.
__global__ __launch_bounds__(512) void k_divresid_r(
    const float* __restrict__ u2, const float* __restrict__ v2, const float* __restrict__ w2,
    const float* __restrict__ p, float* __restrict__ r0, float* __restrict__ r1) {
    __shared__ float lds[2][4][256];
    int tx = threadIdx.x, ty = threadIdx.y, tz = threadIdx.z;
    int y, z, ytile, ztile;
    decode_f2(blockIdx.x, y, z, ytile, ztile);
    int x0 = tx << 2, c = idx3(z, y, x0);

    F4 uc; uc.v = ld4(u2, z, y, x0);
    float uxmS = tx ? u2[c - 1] : UBC, uxpS = (tx < 63) ? u2[c + 4] : 0.f;
    float vym[4], vyp[4], wzm[4], wzp[4];
    row0(v2, z, y - 1, x0, y > 0, vym);
    row0(v2, z, y + 1, x0, y < NY - 1, vyp);
    row0(w2, z - 1, y, x0, z > 0, wzm);
    row0(w2, z + 1, y, x0, z < NZ - 1, wzp);

    F4 pc, pym, pyp, pzm, pzp;
    pc.v  = ld4(p, z, y, x0);
    pym.v = ld4(p, z, y > 0 ? y - 1 : 0, x0);
    pyp.v = ld4(p, z, y < NY - 1 ? y + 1 : y, x0);
    pzm.v = ld4(p, z > 0 ? z - 1 : 0, y, x0);
    pzp.v = ld4(p, z < NZ - 1 ? z + 1 : z, y, x0);
    float pxmS = tx ? p[c - 1] : pc.f[0];
    float pxpS = (tx < 63) ? p[c + 4] : pc.f[3];

    F4 o;
    #pragma unroll
    for (int i = 0; i < 4; i++) {
        float uxm = i ? uc.f[i - 1] : uxmS, uxp = (i < 3) ? uc.f[i + 1] : uxpS;
        float bval = -(0.5f * (uxp - uxm) + 0.5f * (vyp[i] - vym[i])
                       + 0.5f * (wzp[i] - wzm[i])) * RDT;
        float pxm = i ? pc.f[i - 1] : pxmS, pxp = (i < 3) ? pc.f[i + 1] : pxpS;
        float lap = pxm + pxp + pym.f[i] + pyp.f[i] + pzm.f[i] + pzp.f[i] - 6.f * pc.f[i];
        o.f[i] = lap - bval;
    }
    st4(r0, c, o);
    *reinterpret_cast<float4*>(&lds[tz][ty][x0]) = o.v;
    __syncthreads();
    int tid = (tz * 4 + ty) * 64 + tx;
    if (tid < 256) {
        int y1loc = tid >> 7, x1 = tid & 127;
        int xf = x1 << 1, yf = y1loc << 1;
        float s = lds[0][yf][xf]     + lds[0][yf][xf + 1]
                + lds[0][yf + 1][xf] + lds[0][yf + 1][xf + 1]
                + lds[1][yf][xf]     + lds[1][yf][xf + 1]
                + lds[1][yf + 1][xf] + lds[1][yf + 1][xf + 1];
        int y1 = ytile * 2 + y1loc, z1 = ztile;
        r1[(z1 * 64 + y1) * 128 + x1] = 0.125f * s;
    }
}

// K4: coarse down-chain r1(32,64,128) -> r2, r3, r4.  grid(4,4,4), block 512
__global__ __launch_bounds__(512) void k_down(const float* __restrict__ r1,
    float* __restrict__ r2, float* __restrict__ r3, float* __restrict__ r4) {
    __shared__ float l2[4][8][16];
    __shared__ float l3[2][4][8];
    int tid = threadIdx.x;
    int bx = blockIdx.x, by = blockIdx.y, bz = blockIdx.z;
    {
        int tx2 = tid & 15, ty2 = (tid >> 4) & 7, tz2 = tid >> 7;
        int x2 = bx * 16 + tx2, y2 = by * 8 + ty2, z2 = bz * 4 + tz2;
        const float* b0 = &r1[((size_t)(2 * z2) * 64 + 2 * y2) * 128 + 2 * x2];
        float2 a  = *reinterpret_cast<const float2*>(b0);
        float2 bq = *reinterpret_cast<const float2*>(b0 + 128);
        float2 cq = *reinterpret_cast<const float2*>(b0 + 64 * 128);
        float2 dq = *reinterpret_cast<const float2*>(b0 + 64 * 128 + 128);
        float val = 0.125f * (a.x + a.y + bq.x + bq.y + cq.x + cq.y + dq.x + dq.y);
        l2[tz2][ty2][tx2] = val;
        r2[((z2 * 32) + y2) * 64 + x2] = val;
    }
    __syncthreads();
    if (tid < 64) {
        int tx3 = tid & 7, ty3 = (tid >> 3) & 3, tz3 = tid >> 5;
        float s = l2[2*tz3][2*ty3][2*tx3]     + l2[2*tz3][2*ty3][2*tx3+1]
                + l2[2*tz3][2*ty3+1][2*tx3]   + l2[2*tz3][2*ty3+1][2*tx3+1]
                + l2[2*tz3+1][2*ty3][2*tx3]   + l2[2*tz3+1][2*ty3][2*tx3+1]
                + l2[2*tz3+1][2*ty3+1][2*tx3] + l2[2*tz3+1][2*ty3+1][2*tx3+1];
        float val = 0.125f * s;
        l3[tz3][ty3][tx3] = val;
        int x3 = bx * 8 + tx3, y3 = by * 4 + ty3, z3 = bz * 2 + tz3;
        r3[((z3 * 16) + y3) * 32 + x3] = val;
    }
    __syncthreads();
    if (tid < 8) {
        int tx4 = tid & 3, ty4 = tid >> 2;
        float s = l3[0][2*ty4][2*tx4]   + l3[0][2*ty4][2*tx4+1]
                + l3[0][2*ty4+1][2*tx4] + l3[0][2*ty4+1][2*tx4+1]
                + l3[1][2*ty4][2*tx4]   + l3[1][2*ty4][2*tx4+1]
                + l3[1][2*ty4+1][2*tx4] + l3[1][2*ty4+1][2*tx4+1];
        int x4 = bx * 4 + tx4, y4 = by * 2 + ty4, z4 = bz;
        r4[((z4 * 8) + y4) * 16 + x4] = 0.125f * s;
    }
}

__device__ __forceinline__ float a4p(const float* __restrict__ r4, int z3, int y3, int x3) {
    if ((unsigned)z3 >= 8u || (unsigned)y3 >= 16u || (unsigned)x3 >= 32u) return 0.f;
    return r4[(((z3 >> 1) * 8) + (y3 >> 1)) * 16 + (x3 >> 1)] * IDIAG;
}

// K5: fused coarse up-chain: A=r4/diag -> B(LDS) -> C+halo(LDS) -> D(level-1 out)
__global__ __launch_bounds__(512) void k_upf(const float* __restrict__ r4,
    const float* __restrict__ r3, const float* __restrict__ r2,
    const float* __restrict__ r1, float* __restrict__ D) {
    __shared__ float Bl[4][6][10];
    __shared__ float Cl[6][10][18];
    int tid = threadIdx.x;
    int bx = blockIdx.x, by = blockIdx.y, bz = blockIdx.z;
    int B0z = bz * 2 - 1, B0y = by * 4 - 1, B0x = bx * 8 - 1;
    if (tid < 240) {
        int lx = tid % 10, ly = (tid / 10) % 6, lz = tid / 60;
        int z3 = B0z + lz, y3 = B0y + ly, x3 = B0x + lx;
        float val = 0.f;
        if ((unsigned)z3 < 8u && (unsigned)y3 < 16u && (unsigned)x3 < 32u) {
            float wcn = r4[(((z3 >> 1) * 8) + (y3 >> 1)) * 16 + (x3 >> 1)] * IDIAG;
            float lap = a4p(r4, z3 - 1, y3, x3) + a4p(r4, z3 + 1, y3, x3)
                      + a4p(r4, z3, y3 - 1, x3) + a4p(r4, z3, y3 + 1, x3)
                      + a4p(r4, z3, y3, x3 - 1) + a4p(r4, z3, y3, x3 + 1) - 6.f * wcn;
            val = wcn - lap * IDIAG + r3[((z3 * 16) + y3) * 32 + x3] * IDIAG;
        }
        Bl[lz][ly][lx] = val;
    }
    __syncthreads();
    int C0z = bz * 4 - 1, C0y = by * 8 - 1, C0x = bx * 16 - 1;
    auto pB = [&](int z2, int y2, int x2) -> float {
        if ((unsigned)z2 >= 16u || (unsigned)y2 >= 32u || (unsigned)x2 >= 64u) return 0.f;
        return Bl[(z2 >> 1) - B0z][(y2 >> 1) - B0y][(x2 >> 1) - B0x];
    };
    for (int i = tid; i < 1080; i += 512) {
        int lx = i % 18, ly = (i / 18) % 10, lz = i / 180;
        int z2 = C0z + lz, y2 = C0y + ly, x2 = C0x + lx;
        float val = 0.f;
        if ((unsigned)z2 < 16u && (unsigned)y2 < 32u && (unsigned)x2 < 64u) {
            float wB = Bl[(z2 >> 1) - B0z][(y2 >> 1) - B0y][(x2 >> 1) - B0x];
            float lap = pB(z2 - 1, y2, x2) + pB(z2 + 1, y2, x2)
                      + pB(z2, y2 - 1, x2) + pB(z2, y2 + 1, x2)
                      + pB(z2, y2, x2 - 1) + pB(z2, y2, x2 + 1) - 6.f * wB;
            val = wB - lap * IDIAG + r2[((z2 * 32) + y2) * 64 + x2] * IDIAG;
        }
        Cl[lz][ly][lx] = val;
    }
    __syncthreads();
    auto pC = [&](int z1, int y1, int x1) -> float {
        if ((unsigned)z1 >= 32u || (unsigned)y1 >= 64u || (unsigned)x1 >= 128u) return 0.f;
        return Cl[(z1 >> 1) - C0z][(y1 >> 1) - C0y][(x1 >> 1) - C0x];
    };
    for (int i = tid; i < 4096; i += 512) {
        int lx = i & 31, ly = (i >> 5) & 15, lz = i >> 9;
        int z1 = bz * 8 + lz, y1 = by * 16 + ly, x1 = bx * 32 + lx;
        float wC = Cl[(z1 >> 1) - C0z][(y1 >> 1) - C0y][(x1 >> 1) - C0x];
        float lap = pC(z1 - 1, y1, x1) + pC(z1 + 1, y1, x1)
                  + pC(z1, y1 - 1, x1) + pC(z1, y1 + 1, x1)
                  + pC(z1, y1, x1 - 1) + pC(z1, y1, x1 + 1) - 6.f * wC;
        int idx = (z1 * 64 + y1) * 128 + x1;
        D[idx] = wC - lap * IDIAG + r1[idx] * IDIAG;
    }
}

// K6: iter0 p-update + iter1 residual (linearity) + fused restriction of r1res.
__global__ __launch_bounds__(512) void k_pup_resid_r(
    const float* __restrict__ pin, const float* __restrict__ D0,
    const float* __restrict__ r0, float* __restrict__ p1, float* __restrict__ r1res,
    float* __restrict__ r1) {
    __shared__ float lds[2][4][256];
    int tx = threadIdx.x, ty = threadIdx.y, tz = threadIdx.z;
    int y, z, ytile, ztile;
    decode_f2(blockIdx.x, y, z, ytile, ztile);
    int x0 = tx << 2, c = idx3(z, y, x0);
    int cz = z >> 1, cy = y >> 1, cx0 = tx << 1;

    const float* Drow = &D0[(cz * 64 + cy) * 128];
    float cr[4];
    cr[1] = Drow[cx0]; cr[2] = Drow[cx0 + 1];
    cr[0] = tx ? Drow[cx0 - 1] : cr[1];
    cr[3] = (tx < 63) ? Drow[cx0 + 2] : cr[2];
    int cym = y ? (y - 1) >> 1 : 0, cyp = (y < NY - 1) ? (y + 1) >> 1 : cy;
    int czm = z ? (z - 1) >> 1 : 0, czp = (z < NZ - 1) ? (z + 1) >> 1 : cz;
    float2 dym = *reinterpret_cast<const float2*>(&D0[(cz * 64 + cym) * 128 + cx0]);
    float2 dyp = *reinterpret_cast<const float2*>(&D0[(cz * 64 + cyp) * 128 + cx0]);
    float2 dzm = *reinterpret_cast<const float2*>(&D0[(czm * 64 + cy) * 128 + cx0]);
    float2 dzp = *reinterpret_cast<const float2*>(&D0[(czp * 64 + cy) * 128 + cx0]);

    F4 rc, rym, ryp, rzm, rzp, pin4;
    rc.v  = ld4(r0, z, y, x0);
    rym.v = ld4(r0, z, y > 0 ? y - 1 : 0, x0);
    ryp.v = ld4(r0, z, y < NY - 1 ? y + 1 : y, x0);
    rzm.v = ld4(r0, z > 0 ? z - 1 : 0, y, x0);
    rzp.v = ld4(r0, z < NZ - 1 ? z + 1 : z, y, x0);
    pin4.v = ld4(pin, z, y, x0);
    float rxmS = tx ? r0[c - 1] : rc.f[0];
    float rxpS = (tx < 63) ? r0[c + 4] : rc.f[3];

    F4 op1, ores;
    #pragma unroll
    for (int i = 0; i < 4; i++) {
        float Dc  = cr[1 + (i >> 1)];
        float Dxm = (i == 0) ? cr[0] : cr[1 + ((i - 1) >> 1)];
        float Dxp = (i == 3) ? cr[3] : cr[1 + ((i + 1) >> 1)];
        float Dym = (i < 2) ? dym.x : dym.y;
        float Dyp = (i < 2) ? dyp.x : dyp.y;
        float Dzm = (i < 2) ? dzm.x : dzm.y;
        float Dzp = (i < 2) ? dzp.x : dzp.y;
        float lapD = Dxm + Dxp + Dym + Dyp + Dzm + Dzp - 6.f * Dc;
        float rxm = i ? rc.f[i - 1] : rxmS, rxp = (i < 3) ? rc.f[i + 1] : rxpS;
        float lapR = rxm + rxp + rym.f[i] + ryp.f[i] + rzm.f[i] + rzp.f[i] - 6.f * rc.f[i];
        op1.f[i]  = pin4.f[i] - Dc + rc.f[i] * SIXTH;
        ores.f[i] = rc.f[i] - lapD + lapR * SIXTH;
    }
    st4(p1, c, op1); st4(r1res, c, ores);
    *reinterpret_cast<float4*>(&lds[tz][ty][x0]) = ores.v;
    __syncthreads();
    int tid = (tz * 4 + ty) * 64 + tx;
    if (tid < 256) {
        int y1loc = tid >> 7, x1 = tid & 127;
        int xf = x1 << 1, yf = y1loc << 1;
        float s = lds[0][yf][xf]     + lds[0][yf][xf + 1]
                + lds[0][yf + 1][xf] + lds[0][yf + 1][xf + 1]
                + lds[1][yf][xf]     + lds[1][yf][xf + 1]
                + lds[1][yf + 1][xf] + lds[1][yf + 1][xf + 1];
        int y1 = ytile * 2 + y1loc, z1 = ztile;
        r1[(z1 * 64 + y1) * 128 + x1] = 0.125f * s;
    }
}

// K7: final p-update: p2 = p1 - prol(D1) + r1res/6 ; wmg = prol(D1)
__global__ __launch_bounds__(256) void k_pup2(
    const float* __restrict__ D1, const float* __restrict__ r1res,
    float* __restrict__ pIO, float* __restrict__ wmg) {
    int tx = threadIdx.x, y = blockIdx.x * 4 + threadIdx.y, z = blockIdx.y;
    int x0 = tx << 2, c = idx3(z, y, x0);
    int cz = z >> 1, cy = y >> 1, cx0 = tx << 1;
    float2 d2 = *reinterpret_cast<const float2*>(&D1[(cz * 64 + cy) * 128 + cx0]);
    F4 rr, pp; rr.v = ld4(r1res, z, y, x0); pp.v = ld4(pIO, z, y, x0);
    F4 op, ow;
    #pragma unroll
    for (int i = 0; i < 4; i++) {
        float wv = (i < 2) ? d2.x : d2.y;
        op.f[i] = pp.f[i] - wv + rr.f[i] * SIXTH;
        ow.f[i] = wv;
    }
    st4(pIO, c, op); st4(wmg, c, ow);
}

// K8: projection + final solid_body; LDS sharing of p rows
__global__ __launch_bounds__(256) void k_final(
    const float* __restrict__ p,
    const float* __restrict__ u2, const float* __restrict__ v2, const float* __restrict__ w2,
    const float* __restrict__ sg,
    float* __restrict__ uo, float* __restrict__ vo, float* __restrict__ wo) {
    __shared__ __align__(16) float sp[6][256];
    int tx = threadIdx.x, ty = threadIdx.y, y, z;
    decode_f(blockIdx.x, y, z);
    int x0 = tx << 2, c = idx3(z, y, x0);
    F4 pc; pc.v = ld4(p, z, y, x0);
    #pragma unroll
    for (int i = 0; i < 4; i++) sp[ty + 1][x0 + i] = pc.f[i];
    if (ty == 0) {
        F4 pp; pp.v = ld4(p, z, y > 0 ? y - 1 : 0, x0);
        #pragma unroll
        for (int i = 0; i < 4; i++) sp[0][x0 + i] = pp.f[i];
    } else if (ty == 3) {
        F4 pp; pp.v = ld4(p, z, y + 1 < NY ? y + 1 : NY - 1, x0);
        #pragma unroll
        for (int i = 0; i < 4; i++) sp[5][x0 + i] = pp.f[i];
    }
    __syncthreads();

    F4 Pym, Pyp;
    Pym.v = ldsrow(sp[ty], x0);
    Pyp.v = ldsrow(sp[ty + 2], x0);
    F4 pzm, pzp;
    pzm.v = ld4(p, z > 0 ? z - 1 : 0, y, x0);
    pzp.v = ld4(p, z < NZ - 1 ? z + 1 : z, y, x0);
    float pxmS = tx ? sp[ty + 1][x0 - 1] : pc.f[0];
    float pxpS = (tx < 63) ? sp[ty + 1][x0 + 4] : pc.f[3];

    F4 sc; sc.v = ld4(sg, z, y, x0);
    F4 a, b, cc; a.v = ld4(u2, z, y, x0); b.v = ld4(v2, z, y, x0); cc.v = ld4(w2, z, y, x0);
    F4 ou, ov, ow;
    #pragma unroll
    for (int i = 0; i < 4; i++) {
        float pxm = i ? pc.f[i - 1] : pxmS, pxp = (i < 3) ? pc.f[i + 1] : pxpS;
        float inv = frcp(1.f + DT * sc.f[i]);
        ou.f[i] = (a.f[i]  - 0.5f * (pxp - pxm) * DT) * inv;
        ov.f[i] = (b.f[i]  - 0.5f * (Pyp.f[i] - Pym.f[i]) * DT) * inv;
        ow.f[i] = (cc.f[i] - 0.5f * (pzp.f[i] - pzm.f[i]) * DT) * inv;
    }
    st4(uo, c, ou); st4(vo, c, ov); st4(wo, c, ow);
}

extern "C" void kernel_launch(void* const* d_in, const int* in_sizes, int n_in,
                              void* d_out, int out_size, void* d_ws, size_t ws_size,
                              hipStream_t stream) {
    const float* in_u  = (const float*)d_in[0];
    const float* in_v  = (const float*)d_in[1];
    const float* in_w  = (const float*)d_in[2];
    const float* in_p  = (const float*)d_in[3];
    const float* in_sg = (const float*)d_in[4];

    float* out   = (float*)d_out;
    float* O_u   = out;                      // bu -> r1res -> u_out
    float* O_v   = out + (size_t)NTOT;       // bv -> v_out
    float* O_w   = out + (size_t)2 * NTOT;   // bw -> w_out
    float* O_p   = out + (size_t)3 * NTOT;   // p1 -> p2
    float* O_wmg = out + (size_t)4 * NTOT;   // r0 -> wmg
    float* O_r   = out + (size_t)5 * NTOT;   // final coarsest residual (512)

    float* ws  = (float*)d_ws;
    float* A0  = ws;                          // u2
    float* A1  = ws + (size_t)NTOT;           // v2
    float* A2  = ws + (size_t)2 * NTOT;       // w2
    float* r1  = ws + (size_t)3 * NTOT;       // 262144
    float* r2  = r1 + 262144;                 // 32768
    float* r3  = r2 + 32768;                  // 4096
    float* r4w = r3 + 4096;                   // 512
    float* Dw  = r4w + 512;                   // 262144

    dim3 gF(2048);             dim3 bF(64, 4);
    dim3 gF2(1024);            dim3 bF2(64, 4, 2);
    dim3 gP(NY / 4, NZ);
    dim3 gC(4, 4, 4);

    k_predict     <<<gF,  bF,  0, stream>>>(in_u, in_v, in_w, in_p, in_sg, O_u, O_v, O_w);
    k_correct     <<<gF,  bF,  0, stream>>>(in_u, in_v, in_w, in_sg, O_u, O_v, O_w, in_p, A0, A1, A2);
    k_divresid_r  <<<gF2, bF2, 0, stream>>>(A0, A1, A2, in_p, O_wmg /*r0*/, r1);

    // --- MG iteration 0 ---
    k_down        <<<gC, dim3(512), 0, stream>>>(r1, r2, r3, r4w);
    k_upf         <<<gC, dim3(512), 0, stream>>>(r4w, r3, r2, r1, Dw);
    k_pup_resid_r <<<gF2, bF2, 0, stream>>>(in_p, Dw, O_wmg, O_p /*p1*/, O_u /*r1res*/, r1);

    // --- MG iteration 1 ---
    k_down        <<<gC, dim3(512), 0, stream>>>(r1, r2, r3, O_r);
    k_upf         <<<gC, dim3(512), 0, stream>>>(O_r, r3, r2, r1, Dw);
    k_pup2        <<<gP, bF, 0, stream>>>(Dw, O_u /*r1res*/, O_p /*p1->p2*/, O_wmg /*wmg*/);

    k_final       <<<gF, bF, 0, stream>>>(O_p, A0, A1, A2, in_sg, O_u, O_v, O_w);
}

// Round 11
// 88.875 us; speedup vs baseline: 1.3319x; 1.0354x over previous
//
#include <hip/hip_runtime.h>

// ---------------------------------------------------------------------------
// AI4Urban one-timestep NS solver on 64x128x256, f32.  Round 11:
//  = R10 champion (92.0us) with k_pup2+k_final fused into k_pfin:
//  p2 = p1 - prol(D1) + r1res/6 is POINTWISE, so grad(ep(p2)) is recomputed
//  from cheap clamped loads of p1/r1res/D1 (k_pup_resid_r's load pattern).
//  Buffer re-choreography to avoid aliasing: bu/bv/bw->ws; u2/v2/w2->O_u/v/w
//  (center-only read->write in k_pfin, race-free); p1->ws.B0, r1res->ws.B1
//  (dead bu/bv slots; ws unchanged ~27.4MB).  9 dispatches.
// ---------------------------------------------------------------------------

constexpr int NZ = 64, NY = 128, NX = 256;
constexpr int NTOT = NZ * NY * NX;
constexpr float DT  = 0.01f;
constexpr float RDT = 100.0f;          // 1/DT
constexpr float RE  = 0.001f;
constexpr float UBC = -1.0f;
constexpr float SIXTH = 1.0f / 6.0f;
constexpr float IDIAG = -1.0f / 6.0f;  // 1/DIAG, DIAG=-6

__device__ __forceinline__ float frcp(float x) { return __builtin_amdgcn_rcpf(x); }

__device__ __forceinline__ int idx3(int z, int y, int x) {
    return (z * NY + y) * NX + x;
}

union F4 { float4 v; float f[4]; };

__device__ __forceinline__ float4 ld4(const float* __restrict__ f, int z, int y, int x0) {
    return *reinterpret_cast<const float4*>(&f[idx3(z, y, x0)]);
}
__device__ __forceinline__ void st4(float* __restrict__ f, int c, const F4& a) {
    *reinterpret_cast<float4*>(&f[c]) = a.v;
}
__device__ __forceinline__ float4 ldsrow(const float* r, int x0) {
    return *reinterpret_cast<const float4*>(&r[x0]);
}

__device__ __forceinline__ void zero4(float o[4]) {
    #pragma unroll
    for (int i = 0; i < 4; i++) o[i] = 0.f;
}

__device__ __forceinline__ void row0(const float* __restrict__ f, int z, int y, int x0,
                                     bool ok, float o[4]) {
    if (ok) { F4 a; a.v = ld4(f, z, y, x0);
        #pragma unroll
        for (int i = 0; i < 4; i++) o[i] = a.f[i];
    } else {
        zero4(o);
    }
}
__device__ __forceinline__ void row3s(const float* __restrict__ u, const float* __restrict__ v,
                                      const float* __restrict__ w, const float* __restrict__ sg,
                                      int z, int y, int x0, bool ok,
                                      float uo[4], float vo[4], float wo[4]) {
    if (ok) {
        F4 a, b, c, s;
        a.v = ld4(u, z, y, x0); b.v = ld4(v, z, y, x0);
        c.v = ld4(w, z, y, x0); s.v = ld4(sg, z, y, x0);
        #pragma unroll
        for (int i = 0; i < 4; i++) {
            float iv = frcp(1.f + DT * s.f[i]);
            uo[i] = a.f[i] * iv; vo[i] = b.f[i] * iv; wo[i] = c.f[i] * iv;
        }
    } else {
        zero4(uo); zero4(vo); zero4(wo);
    }
}

// XCD z-slab swizzle decode: 2048 blocks, block (64,4).
__device__ __forceinline__ void decode_f(int d, int& y, int& z) {
    int k = d & 7, j = d >> 3;
    z = 8 * k + (j >> 5);
    y = (j & 31) * 4 + threadIdx.y;
}
// 1024 blocks, block (64,4,2): XCD k owns ztile in [4k,4k+4).
__device__ __forceinline__ void decode_f2(int d, int& y, int& z, int& ytile, int& ztile) {
    int k = d & 7, j = d >> 3;
    ztile = 4 * k + (j >> 5);
    ytile = j & 31;
    z = ztile * 2 + threadIdx.z;
    y = ytile * 4 + threadIdx.y;
}

// K1: predictor, solid_body fused; LDS row-sharing across the 4-y block
__global__ __launch_bounds__(256) void k_predict(
    const float* __restrict__ u, const float* __restrict__ v, const float* __restrict__ w,
    const float* __restrict__ p, const float* __restrict__ sg,
    float* __restrict__ bu, float* __restrict__ bv, float* __restrict__ bw) {
    __shared__ __align__(16) float su[6][256], sv[6][256], sw[6][256], sp[6][256];
    int tx = threadIdx.x, ty = threadIdx.y, y, z;
    decode_f(blockIdx.x, y, z);
    int x0 = tx << 2, c = idx3(z, y, x0);

    F4 sc; sc.v = ld4(sg, z, y, x0);
    F4 u4, v4, w4; u4.v = ld4(u, z, y, x0); v4.v = ld4(v, z, y, x0); w4.v = ld4(w, z, y, x0);
    F4 pc; pc.v = ld4(p, z, y, x0);
    float inv[4], uc[4], vc[4], wc[4];
    #pragma unroll
    for (int i = 0; i < 4; i++) {
        inv[i] = frcp(1.f + DT * sc.f[i]);
        uc[i] = u4.f[i] * inv[i]; vc[i] = v4.f[i] * inv[i]; wc[i] = w4.f[i] * inv[i];
        su[ty + 1][x0 + i] = uc[i]; sv[ty + 1][x0 + i] = vc[i];
        sw[ty + 1][x0 + i] = wc[i]; sp[ty + 1][x0 + i] = pc.f[i];
    }
    if (ty == 0) {
        int ym = y - 1;
        if (ym >= 0) {
            F4 a, b, c2, s;
            a.v = ld4(u, z, ym, x0); b.v = ld4(v, z, ym, x0);
            c2.v = ld4(w, z, ym, x0); s.v = ld4(sg, z, ym, x0);
            #pragma unroll
            for (int i = 0; i < 4; i++) {
                float iv = frcp(1.f + DT * s.f[i]);
                su[0][x0 + i] = a.f[i] * iv; sv[0][x0 + i] = b.f[i] * iv;
                sw[0][x0 + i] = c2.f[i] * iv;
            }
        } else {
            #pragma unroll
            for (int i = 0; i < 4; i++) { su[0][x0+i] = 0.f; sv[0][x0+i] = 0.f; sw[0][x0+i] = 0.f; }
        }
        F4 pp; pp.v = ld4(p, z, ym >= 0 ? ym : 0, x0);
        #pragma unroll
        for (int i = 0; i < 4; i++) sp[0][x0 + i] = pp.f[i];
    } else if (ty == 3) {
        int yp = y + 1;
        if (yp < NY) {
            F4 a, b, c2, s;
            a.v = ld4(u, z, yp, x0); b.v = ld4(v, z, yp, x0);
            c2.v = ld4(w, z, yp, x0); s.v = ld4(sg, z, yp, x0);
            #pragma unroll
            for (int i = 0; i < 4; i++) {
                float iv = frcp(1.f + DT * s.f[i]);
                su[5][x0 + i] = a.f[i] * iv; sv[5][x0 + i] = b.f[i] * iv;
                sw[5][x0 + i] = c2.f[i] * iv;
            }
        } else {
            #pragma unroll
            for (int i = 0; i < 4; i++) { su[5][x0+i] = 0.f; sv[5][x0+i] = 0.f; sw[5][x0+i] = 0.f; }
        }
        F4 pp; pp.v = ld4(p, z, yp < NY ? yp : NY - 1, x0);
        #pragma unroll
        for (int i = 0; i < 4; i++) sp[5][x0 + i] = pp.f[i];
    }
    __syncthreads();

    F4 Uym, Uyp, Vym, Vyp, Wym, Wyp, Pym, Pyp;
    Uym.v = ldsrow(su[ty], x0);     Uyp.v = ldsrow(su[ty + 2], x0);
    Vym.v = ldsrow(sv[ty], x0);     Vyp.v = ldsrow(sv[ty + 2], x0);
    Wym.v = ldsrow(sw[ty], x0);     Wyp.v = ldsrow(sw[ty + 2], x0);
    Pym.v = ldsrow(sp[ty], x0);     Pyp.v = ldsrow(sp[ty + 2], x0);

    float uzm[4], vzm[4], wzm[4], uzp[4], vzp[4], wzp[4];
    row3s(u, v, w, sg, z - 1, y, x0, z > 0,      uzm, vzm, wzm);
    row3s(u, v, w, sg, z + 1, y, x0, z < NZ - 1, uzp, vzp, wzp);
    F4 pzm, pzp;
    pzm.v = ld4(p, z > 0 ? z - 1 : 0, y, x0);
    pzp.v = ld4(p, z < NZ - 1 ? z + 1 : z, y, x0);

    float uxmS = tx ? su[ty + 1][x0 - 1] : UBC;
    float vxmS = tx ? sv[ty + 1][x0 - 1] : 0.f;
    float wxmS = tx ? sw[ty + 1][x0 - 1] : 0.f;
    float uxpS = (tx < 63) ? su[ty + 1][x0 + 4] : 0.f;
    float vxpS = (tx < 63) ? sv[ty + 1][x0 + 4] : 0.f;
    float wxpS = (tx < 63) ? sw[ty + 1][x0 + 4] : 0.f;
    float pxmS = tx ? sp[ty + 1][x0 - 1] : pc.f[0];
    float pxpS = (tx < 63) ? sp[ty + 1][x0 + 4] : pc.f[3];

    F4 obu, obv, obw;
    #pragma unroll
    for (int i = 0; i < 4; i++) {
        float uxm = i ? uc[i - 1] : uxmS, uxp = (i < 3) ? uc[i + 1] : uxpS;
        float vxm = i ? vc[i - 1] : vxmS, vxp = (i < 3) ? vc[i + 1] : vxpS;
        float wxm = i ? wc[i - 1] : wxmS, wxp = (i < 3) ? wc[i + 1] : wxpS;
        float pxm = i ? pc.f[i - 1] : pxmS, pxp = (i < 3) ? pc.f[i + 1] : pxpS;
        float dpx = 0.5f * (pxp - pxm);
        float dpy = 0.5f * (Pyp.f[i] - Pym.f[i]);
        float dpz = 0.5f * (pzp.f[i] - pzm.f[i]);
        float lap_u = uxm + uxp + Uym.f[i] + Uyp.f[i] + uzm[i] + uzp[i] - 6.f * uc[i];
        float lap_v = vxm + vxp + Vym.f[i] + Vyp.f[i] + vzm[i] + vzp[i] - 6.f * vc[i];
        float lap_w = wxm + wxp + Wym.f[i] + Wyp.f[i] + wzm[i] + wzp[i] - 6.f * wc[i];
        float bun = uc[i] + 0.5f * (RE * lap_u * DT
                    - uc[i] * (0.5f * (uxp - uxm)) * DT
                    - vc[i] * (0.5f * (Uyp.f[i] - Uym.f[i])) * DT
                    - wc[i] * (0.5f * (uzp[i] - uzm[i])) * DT) - dpx * DT;
        float bvn = vc[i] + 0.5f * (RE * lap_v * DT
                    - uc[i] * (0.5f * (vxp - vxm)) * DT
                    - vc[i] * (0.5f * (Vyp.f[i] - Vym.f[i])) * DT
                    - wc[i] * (0.5f * (vzp[i] - vzm[i])) * DT) - dpy * DT;
        float bwn = wc[i] + 0.5f * (RE * lap_w * DT
                    - uc[i] * (0.5f * (wxp - wxm)) * DT
                    - vc[i] * (0.5f * (Wyp.f[i] - Wym.f[i])) * DT
                    - wc[i] * (0.5f * (wzp[i] - wzm[i])) * DT) - dpz * DT;
        obu.f[i] = bun * inv[i];
        obv.f[i] = bvn * inv[i];
        obw.f[i] = bwn * inv[i];
    }
    st4(bu, c, obu); st4(bv, c, obv); st4(bw, c, obw);
}

// K2: corrector; LDS row-sharing of bu/bv/bw and p
__global__ __launch_bounds__(256) void k_correct(
    const float* __restrict__ u, const float* __restrict__ v, const float* __restrict__ w,
    const float* __restrict__ sg,
    const float* __restrict__ bu, const float* __restrict__ bv, const float* __restrict__ bw,
    const float* __restrict__ p,
    float* __restrict__ u2, float* __restrict__ v2, float* __restrict__ w2) {
    __shared__ __align__(16) float su[6][256], sv[6][256], sw[6][256], sp[6][256];
    int tx = threadIdx.x, ty = threadIdx.y, y, z;
    decode_f(blockIdx.x, y, z);
    int x0 = tx << 2, c = idx3(z, y, x0);

    F4 sc; sc.v = ld4(sg, z, y, x0);
    F4 u4, v4, w4; u4.v = ld4(u, z, y, x0); v4.v = ld4(v, z, y, x0); w4.v = ld4(w, z, y, x0);
    F4 buc, bvc, bwc; buc.v = ld4(bu, z, y, x0); bvc.v = ld4(bv, z, y, x0); bwc.v = ld4(bw, z, y, x0);
    F4 pc; pc.v = ld4(p, z, y, x0);
    #pragma unroll
    for (int i = 0; i < 4; i++) {
        su[ty + 1][x0 + i] = buc.f[i]; sv[ty + 1][x0 + i] = bvc.f[i];
        sw[ty + 1][x0 + i] = bwc.f[i]; sp[ty + 1][x0 + i] = pc.f[i];
    }
    if (ty == 0) {
        int ym = y - 1;
        if (ym >= 0) {
            F4 a, b, c2;
            a.v = ld4(bu, z, ym, x0); b.v = ld4(bv, z, ym, x0); c2.v = ld4(bw, z, ym, x0);
            #pragma unroll
            for (int i = 0; i < 4; i++) { su[0][x0+i] = a.f[i]; sv[0][x0+i] = b.f[i]; sw[0][x0+i] = c2.f[i]; }
        } else {
            #pragma unroll
            for (int i = 0; i < 4; i++) { su[0][x0+i] = 0.f; sv[0][x0+i] = 0.f; sw[0][x0+i] = 0.f; }
        }
        F4 pp; pp.v = ld4(p, z, ym >= 0 ? ym : 0, x0);
        #pragma unroll
        for (int i = 0; i < 4; i++) sp[0][x0 + i] = pp.f[i];
    } else if (ty == 3) {
        int yp = y + 1;
        if (yp < NY) {
            F4 a, b, c2;
            a.v = ld4(bu, z, yp, x0); b.v = ld4(bv, z, yp, x0); c2.v = ld4(bw, z, yp, x0);
            #pragma unroll
            for (int i = 0; i < 4; i++) { su[5][x0+i] = a.f[i]; sv[5][x0+i] = b.f[i]; sw[5][x0+i] = c2.f[i]; }
        } else {
            #pragma unroll
            for (int i = 0; i < 4; i++) { su[5][x0+i] = 0.f; sv[5][x0+i] = 0.f; sw[5][x0+i] = 0.f; }
        }
        F4 pp; pp.v = ld4(p, z, yp < NY ? yp : NY - 1, x0);
        #pragma unroll
        for (int i = 0; i < 4; i++) sp[5][x0 + i] = pp.f[i];
    }
    __syncthreads();

    F4 Uym, Uyp, Vym, Vyp, Wym, Wyp, Pym, Pyp;
    Uym.v = ldsrow(su[ty], x0);     Uyp.v = ldsrow(su[ty + 2], x0);
    Vym.v = ldsrow(sv[ty], x0);     Vyp.v = ldsrow(sv[ty + 2], x0);
    Wym.v = ldsrow(sw[ty], x0);     Wyp.v = ldsrow(sw[ty + 2], x0);
    Pym.v = ldsrow(sp[ty], x0);     Pyp.v = ldsrow(sp[ty + 2], x0);

    float uzm[4], vzm[4], wzm[4], uzp[4], vzp[4], wzp[4];
    row0(bu, z - 1, y, x0, z > 0, uzm);      row0(bv, z - 1, y, x0, z > 0, vzm);
    row0(bw, z - 1, y, x0, z > 0, wzm);
    row0(bu, z + 1, y, x0, z < NZ - 1, uzp); row0(bv, z + 1, y, x0, z < NZ - 1, vzp);
    row0(bw, z + 1, y, x0, z < NZ - 1, wzp);
    F4 pzm, pzp;
    pzm.v = ld4(p, z > 0 ? z - 1 : 0, y, x0);
    pzp.v = ld4(p, z < NZ - 1 ? z + 1 : z, y, x0);

    float uxmS = tx ? su[ty + 1][x0 - 1] : UBC;
    float vxmS = tx ? sv[ty + 1][x0 - 1] : 0.f;
    float wxmS = tx ? sw[ty + 1][x0 - 1] : 0.f;
    float uxpS = (tx < 63) ? su[ty + 1][x0 + 4] : 0.f;
    float vxpS = (tx < 63) ? sv[ty + 1][x0 + 4] : 0.f;
    float wxpS = (tx < 63) ? sw[ty + 1][x0 + 4] : 0.f;
    float pxmS = tx ? sp[ty + 1][x0 - 1] : pc.f[0];
    float pxpS = (tx < 63) ? sp[ty + 1][x0 + 4] : pc.f[3];

    F4 ou, ov, ow;
    #pragma unroll
    for (int i = 0; i < 4; i++) {
        float inv = frcp(1.f + DT * sc.f[i]);
        float u1c = u4.f[i] * inv, v1c = v4.f[i] * inv, w1c = w4.f[i] * inv;
        float uxm = i ? buc.f[i - 1] : uxmS, uxp = (i < 3) ? buc.f[i + 1] : uxpS;
        float vxm = i ? bvc.f[i - 1] : vxmS, vxp = (i < 3) ? bvc.f[i + 1] : vxpS;
        float wxm = i ? bwc.f[i - 1] : wxmS, wxp = (i < 3) ? bwc.f[i + 1] : wxpS;
        float pxm = i ? pc.f[i - 1] : pxmS, pxp = (i < 3) ? pc.f[i + 1] : pxpS;
        float dpx = 0.5f * (pxp - pxm);
        float dpy = 0.5f * (Pyp.f[i] - Pym.f[i]);
        float dpz = 0.5f * (pzp.f[i] - pzm.f[i]);
        float lap_u = uxm + uxp + Uym.f[i] + Uyp.f[i] + uzm[i] + uzp[i] - 6.f * buc.f[i];
        float lap_v = vxm + vxp + Vym.f[i] + Vyp.f[i] + vzm[i] + vzp[i] - 6.f * bvc.f[i];
        float lap_w = wxm + wxp + Wym.f[i] + Wyp.f[i] + wzm[i] + wzp[i] - 6.f * bwc.f[i];
        float un = u1c + RE * lap_u * DT
                   - buc.f[i] * (0.5f * (uxp - uxm)) * DT
                   - bvc.f[i] * (0.5f * (Uyp.f[i] - Uym.f[i])) * DT
                   - bwc.f[i] * (0.5f * (uzp[i] - uzm[i])) * DT - dpx * DT;
        float vn = v1c + RE * lap_v * DT
                   - buc.f[i] * (0.5f * (vxp - vxm)) * DT
                   - bvc.f[i] * (0.5f * (Vyp.f[i] - Vym.f[i])) * DT
                   - bwc.f[i] * (0.5f * (vzp[i] - vzm[i])) * DT - dpy * DT;
        float wn = w1c + RE * lap_w * DT
                   - buc.f[i] * (0.5f * (wxp - wxm)) * DT
                   - bvc.f[i] * (0.5f * (Wyp.f[i] - Wym.f[i])) * DT
                   - bwc.f[i] * (0.5f * (wzp[i] - wzm[i])) * DT - dpz * DT;
        ou.f[i] = un * inv; ov.f[i] = vn * inv; ow.f[i] = wn * inv;
    }
    st4(u2, c, ou); st4(v2, c, ov); st4(w2, c, ow);
}

// K3: r0 = lap_ep(p) - b (b inline), plus fused level-0->1 restriction of r0.
__global__ __launch_bounds__(512) void k_divresid_r(
    const float* __restrict__ u2, const float* __restrict__ v2, const float* __restrict__ w2,
    const float* __restrict__ p, float* __restrict__ r0, float* __restrict__ r1) {
    __shared__ float lds[2][4][256];
    int tx = threadIdx.x, ty = threadIdx.y, tz = threadIdx.z;
    int y, z, ytile, ztile;
    decode_f2(blockIdx.x, y, z, ytile, ztile);
    int x0 = tx << 2, c = idx3(z, y, x0);

    F4 uc; uc.v = ld4(u2, z, y, x0);
    float uxmS = tx ? u2[c - 1] : UBC, uxpS = (tx < 63) ? u2[c + 4] : 0.f;
    float vym[4], vyp[4], wzm[4], wzp[4];
    row0(v2, z, y - 1, x0, y > 0, vym);
    row0(v2, z, y + 1, x0, y < NY - 1, vyp);
    row0(w2, z - 1, y, x0, z > 0, wzm);
    row0(w2, z + 1, y, x0, z < NZ - 1, wzp);

    F4 pc, pym, pyp, pzm, pzp;
    pc.v  = ld4(p, z, y, x0);
    pym.v = ld4(p, z, y > 0 ? y - 1 : 0, x0);
    pyp.v = ld4(p, z, y < NY - 1 ? y + 1 : y, x0);
    pzm.v = ld4(p, z > 0 ? z - 1 : 0, y, x0);
    pzp.v = ld4(p, z < NZ - 1 ? z + 1 : z, y, x0);
    float pxmS = tx ? p[c - 1] : pc.f[0];
    float pxpS = (tx < 63) ? p[c + 4] : pc.f[3];

    F4 o;
    #pragma unroll
    for (int i = 0; i < 4; i++) {
        float uxm = i ? uc.f[i - 1] : uxmS, uxp = (i < 3) ? uc.f[i + 1] : uxpS;
        float bval = -(0.5f * (uxp - uxm) + 0.5f * (vyp[i] - vym[i])
                       + 0.5f * (wzp[i] - wzm[i])) * RDT;
        float pxm = i ? pc.f[i - 1] : pxmS, pxp = (i < 3) ? pc.f[i + 1] : pxpS;
        float lap = pxm + pxp + pym.f[i] + pyp.f[i] + pzm.f[i] + pzp.f[i] - 6.f * pc.f[i];
        o.f[i] = lap - bval;
    }
    st4(r0, c, o);
    *reinterpret_cast<float4*>(&lds[tz][ty][x0]) = o.v;
    __syncthreads();
    int tid = (tz * 4 + ty) * 64 + tx;
    if (tid < 256) {
        int y1loc = tid >> 7, x1 = tid & 127;
        int xf = x1 << 1, yf = y1loc << 1;
        float s = lds[0][yf][xf]     + lds[0][yf][xf + 1]
                + lds[0][yf + 1][xf] + lds[0][yf + 1][xf + 1]
                + lds[1][yf][xf]     + lds[1][yf][xf + 1]
                + lds[1][yf + 1][xf] + lds[1][yf + 1][xf + 1];
        int y1 = ytile * 2 + y1loc, z1 = ztile;
        r1[(z1 * 64 + y1) * 128 + x1] = 0.125f * s;
    }
}

// K4: coarse down-chain r1(32,64,128) -> r2, r3, r4.  grid(4,4,4), block 512
__global__ __launch_bounds__(512) void k_down(const float* __restrict__ r1,
    float* __restrict__ r2, float* __restrict__ r3, float* __restrict__ r4) {
    __shared__ float l2[4][8][16];
    __shared__ float l3[2][4][8];
    int tid = threadIdx.x;
    int bx = blockIdx.x, by = blockIdx.y, bz = blockIdx.z;
    {
        int tx2 = tid & 15, ty2 = (tid >> 4) & 7, tz2 = tid >> 7;
        int x2 = bx * 16 + tx2, y2 = by * 8 + ty2, z2 = bz * 4 + tz2;
        const float* b0 = &r1[((size_t)(2 * z2) * 64 + 2 * y2) * 128 + 2 * x2];
        float2 a  = *reinterpret_cast<const float2*>(b0);
        float2 bq = *reinterpret_cast<const float2*>(b0 + 128);
        float2 cq = *reinterpret_cast<const float2*>(b0 + 64 * 128);
        float2 dq = *reinterpret_cast<const float2*>(b0 + 64 * 128 + 128);
        float val = 0.125f * (a.x + a.y + bq.x + bq.y + cq.x + cq.y + dq.x + dq.y);
        l2[tz2][ty2][tx2] = val;
        r2[((z2 * 32) + y2) * 64 + x2] = val;
    }
    __syncthreads();
    if (tid < 64) {
        int tx3 = tid & 7, ty3 = (tid >> 3) & 3, tz3 = tid >> 5;
        float s = l2[2*tz3][2*ty3][2*tx3]     + l2[2*tz3][2*ty3][2*tx3+1]
                + l2[2*tz3][2*ty3+1][2*tx3]   + l2[2*tz3][2*ty3+1][2*tx3+1]
                + l2[2*tz3+1][2*ty3][2*tx3]   + l2[2*tz3+1][2*ty3][2*tx3+1]
                + l2[2*tz3+1][2*ty3+1][2*tx3] + l2[2*tz3+1][2*ty3+1][2*tx3+1];
        float val = 0.125f * s;
        l3[tz3][ty3][tx3] = val;
        int x3 = bx * 8 + tx3, y3 = by * 4 + ty3, z3 = bz * 2 + tz3;
        r3[((z3 * 16) + y3) * 32 + x3] = val;
    }
    __syncthreads();
    if (tid < 8) {
        int tx4 = tid & 3, ty4 = tid >> 2;
        float s = l3[0][2*ty4][2*tx4]   + l3[0][2*ty4][2*tx4+1]
                + l3[0][2*ty4+1][2*tx4] + l3[0][2*ty4+1][2*tx4+1]
                + l3[1][2*ty4][2*tx4]   + l3[1][2*ty4][2*tx4+1]
                + l3[1][2*ty4+1][2*tx4] + l3[1][2*ty4+1][2*tx4+1];
        int x4 = bx * 4 + tx4, y4 = by * 2 + ty4, z4 = bz;
        r4[((z4 * 8) + y4) * 16 + x4] = 0.125f * s;
    }
}

__device__ __forceinline__ float a4p(const float* __restrict__ r4, int z3, int y3, int x3) {
    if ((unsigned)z3 >= 8u || (unsigned)y3 >= 16u || (unsigned)x3 >= 32u) return 0.f;
    return r4[(((z3 >> 1) * 8) + (y3 >> 1)) * 16 + (x3 >> 1)] * IDIAG;
}

// K5: fused coarse up-chain: A=r4/diag -> B(LDS) -> C+halo(LDS) -> D(level-1 out)
__global__ __launch_bounds__(512) void k_upf(const float* __restrict__ r4,
    const float* __restrict__ r3, const float* __restrict__ r2,
    const float* __restrict__ r1, float* __restrict__ D) {
    __shared__ float Bl[4][6][10];
    __shared__ float Cl[6][10][18];
    int tid = threadIdx.x;
    int bx = blockIdx.x, by = blockIdx.y, bz = blockIdx.z;
    int B0z = bz * 2 - 1, B0y = by * 4 - 1, B0x = bx * 8 - 1;
    if (tid < 240) {
        int lx = tid % 10, ly = (tid / 10) % 6, lz = tid / 60;
        int z3 = B0z + lz, y3 = B0y + ly, x3 = B0x + lx;
        float val = 0.f;
        if ((unsigned)z3 < 8u && (unsigned)y3 < 16u && (unsigned)x3 < 32u) {
            float wcn = r4[(((z3 >> 1) * 8) + (y3 >> 1)) * 16 + (x3 >> 1)] * IDIAG;
            float lap = a4p(r4, z3 - 1, y3, x3) + a4p(r4, z3 + 1, y3, x3)
                      + a4p(r4, z3, y3 - 1, x3) + a4p(r4, z3, y3 + 1, x3)
                      + a4p(r4, z3, y3, x3 - 1) + a4p(r4, z3, y3, x3 + 1) - 6.f * wcn;
            val = wcn - lap * IDIAG + r3[((z3 * 16) + y3) * 32 + x3] * IDIAG;
        }
        Bl[lz][ly][lx] = val;
    }
    __syncthreads();
    int C0z = bz * 4 - 1, C0y = by * 8 - 1, C0x = bx * 16 - 1;
    auto pB = [&](int z2, int y2, int x2) -> float {
        if ((unsigned)z2 >= 16u || (unsigned)y2 >= 32u || (unsigned)x2 >= 64u) return 0.f;
        return Bl[(z2 >> 1) - B0z][(y2 >> 1) - B0y][(x2 >> 1) - B0x];
    };
    for (int i = tid; i < 1080; i += 512) {
        int lx = i % 18, ly = (i / 18) % 10, lz = i / 180;
        int z2 = C0z + lz, y2 = C0y + ly, x2 = C0x + lx;
        float val = 0.f;
        if ((unsigned)z2 < 16u && (unsigned)y2 < 32u && (unsigned)x2 < 64u) {
            float wB = Bl[(z2 >> 1) - B0z][(y2 >> 1) - B0y][(x2 >> 1) - B0x];
            float lap = pB(z2 - 1, y2, x2) + pB(z2 + 1, y2, x2)
                      + pB(z2, y2 - 1, x2) + pB(z2, y2 + 1, x2)
                      + pB(z2, y2, x2 - 1) + pB(z2, y2, x2 + 1) - 6.f * wB;
            val = wB - lap * IDIAG + r2[((z2 * 32) + y2) * 64 + x2] * IDIAG;
        }
        Cl[lz][ly][lx] = val;
    }
    __syncthreads();
    auto pC = [&](int z1, int y1, int x1) -> float {
        if ((unsigned)z1 >= 32u || (unsigned)y1 >= 64u || (unsigned)x1 >= 128u) return 0.f;
        return Cl[(z1 >> 1) - C0z][(y1 >> 1) - C0y][(x1 >> 1) - C0x];
    };
    for (int i = tid; i < 4096; i += 512) {
        int lx = i & 31, ly = (i >> 5) & 15, lz = i >> 9;
        int z1 = bz * 8 + lz, y1 = by * 16 + ly, x1 = bx * 32 + lx;
        float wC = Cl[(z1 >> 1) - C0z][(y1 >> 1) - C0y][(x1 >> 1) - C0x];
        float lap = pC(z1 - 1, y1, x1) + pC(z1 + 1, y1, x1)
                  + pC(z1, y1 - 1, x1) + pC(z1, y1 + 1, x1)
                  + pC(z1, y1, x1 - 1) + pC(z1, y1, x1 + 1) - 6.f * wC;
        int idx = (z1 * 64 + y1) * 128 + x1;
        D[idx] = wC - lap * IDIAG + r1[idx] * IDIAG;
    }
}

// K6: iter0 p-update + iter1 residual (linearity) + fused restriction of r1res.
__global__ __launch_bounds__(512) void k_pup_resid_r(
    const float* __restrict__ pin, const float* __restrict__ D0,
    const float* __restrict__ r0, float* __restrict__ p1, float* __restrict__ r1res,
    float* __restrict__ r1) {
    __shared__ float lds[2][4][256];
    int tx = threadIdx.x, ty = threadIdx.y, tz = threadIdx.z;
    int y, z, ytile, ztile;
    decode_f2(blockIdx.x, y, z, ytile, ztile);
    int x0 = tx << 2, c = idx3(z, y, x0);
    int cz = z >> 1, cy = y >> 1, cx0 = tx << 1;

    const float* Drow = &D0[(cz * 64 + cy) * 128];
    float cr[4];
    cr[1] = Drow[cx0]; cr[2] = Drow[cx0 + 1];
    cr[0] = tx ? Drow[cx0 - 1] : cr[1];
    cr[3] = (tx < 63) ? Drow[cx0 + 2] : cr[2];
    int cym = y ? (y - 1) >> 1 : 0, cyp = (y < NY - 1) ? (y + 1) >> 1 : cy;
    int czm = z ? (z - 1) >> 1 : 0, czp = (z < NZ - 1) ? (z + 1) >> 1 : cz;
    float2 dym = *reinterpret_cast<const float2*>(&D0[(cz * 64 + cym) * 128 + cx0]);
    float2 dyp = *reinterpret_cast<const float2*>(&D0[(cz * 64 + cyp) * 128 + cx0]);
    float2 dzm = *reinterpret_cast<const float2*>(&D0[(czm * 64 + cy) * 128 + cx0]);
    float2 dzp = *reinterpret_cast<const float2*>(&D0[(czp * 64 + cy) * 128 + cx0]);

    F4 rc, rym, ryp, rzm, rzp, pin4;
    rc.v  = ld4(r0, z, y, x0);
    rym.v = ld4(r0, z, y > 0 ? y - 1 : 0, x0);
    ryp.v = ld4(r0, z, y < NY - 1 ? y + 1 : y, x0);
    rzm.v = ld4(r0, z > 0 ? z - 1 : 0, y, x0);
    rzp.v = ld4(r0, z < NZ - 1 ? z + 1 : z, y, x0);
    pin4.v = ld4(pin, z, y, x0);
    float rxmS = tx ? r0[c - 1] : rc.f[0];
    float rxpS = (tx < 63) ? r0[c + 4] : rc.f[3];

    F4 op1, ores;
    #pragma unroll
    for (int i = 0; i < 4; i++) {
        float Dc  = cr[1 + (i >> 1)];
        float Dxm = (i == 0) ? cr[0] : cr[1 + ((i - 1) >> 1)];
        float Dxp = (i == 3) ? cr[3] : cr[1 + ((i + 1) >> 1)];
        float Dym = (i < 2) ? dym.x : dym.y;
        float Dyp = (i < 2) ? dyp.x : dyp.y;
        float Dzm = (i < 2) ? dzm.x : dzm.y;
        float Dzp = (i < 2) ? dzp.x : dzp.y;
        float lapD = Dxm + Dxp + Dym + Dyp + Dzm + Dzp - 6.f * Dc;
        float rxm = i ? rc.f[i - 1] : rxmS, rxp = (i < 3) ? rc.f[i + 1] : rxpS;
        float lapR = rxm + rxp + rym.f[i] + ryp.f[i] + rzm.f[i] + rzp.f[i] - 6.f * rc.f[i];
        op1.f[i]  = pin4.f[i] - Dc + rc.f[i] * SIXTH;
        ores.f[i] = rc.f[i] - lapD + lapR * SIXTH;
    }
    st4(p1, c, op1); st4(r1res, c, ores);
    *reinterpret_cast<float4*>(&lds[tz][ty][x0]) = ores.v;
    __syncthreads();
    int tid = (tz * 4 + ty) * 64 + tx;
    if (tid < 256) {
        int y1loc = tid >> 7, x1 = tid & 127;
        int xf = x1 << 1, yf = y1loc << 1;
        float s = lds[0][yf][xf]     + lds[0][yf][xf + 1]
                + lds[0][yf + 1][xf] + lds[0][yf + 1][xf + 1]
                + lds[1][yf][xf]     + lds[1][yf][xf + 1]
                + lds[1][yf + 1][xf] + lds[1][yf + 1][xf + 1];
        int y1 = ytile * 2 + y1loc, z1 = ztile;
        r1[(z1 * 64 + y1) * 128 + x1] = 0.125f * s;
    }
}

// K7: fused final: p2 = p1 - prol(D1) + r1res/6 (recomputed at all 7 stencil
// points from clamped loads), then projection + solid_body.
// Reads u2/v2/w2 center-only from O_u/O_v/O_w and overwrites them (race-free).
__global__ __launch_bounds__(256) void k_pfin(
    const float* __restrict__ p1, const float* __restrict__ rr,
    const float* __restrict__ D1,
    float* __restrict__ uIO, float* __restrict__ vIO, float* __restrict__ wIO,
    const float* __restrict__ sg,
    float* __restrict__ pout, float* __restrict__ wmg) {
    int tx = threadIdx.x, y, z;
    decode_f(blockIdx.x, y, z);
    int x0 = tx << 2, c = idx3(z, y, x0);
    int cz = z >> 1, cy = y >> 1, cx0 = tx << 1;

    const float* Drow = &D1[(cz * 64 + cy) * 128];
    float cr[4];
    cr[1] = Drow[cx0]; cr[2] = Drow[cx0 + 1];
    cr[0] = tx ? Drow[cx0 - 1] : cr[1];
    cr[3] = (tx < 63) ? Drow[cx0 + 2] : cr[2];
    int cym = y ? (y - 1) >> 1 : 0, cyp = (y < NY - 1) ? (y + 1) >> 1 : cy;
    int czm = z ? (z - 1) >> 1 : 0, czp = (z < NZ - 1) ? (z + 1) >> 1 : cz;
    float2 dym = *reinterpret_cast<const float2*>(&D1[(cz * 64 + cym) * 128 + cx0]);
    float2 dyp = *reinterpret_cast<const float2*>(&D1[(cz * 64 + cyp) * 128 + cx0]);
    float2 dzm = *reinterpret_cast<const float2*>(&D1[(czm * 64 + cy) * 128 + cx0]);
    float2 dzp = *reinterpret_cast<const float2*>(&D1[(czp * 64 + cy) * 128 + cx0]);

    F4 pc, pym, pyp, pzm, pzp;
    pc.v  = ld4(p1, z, y, x0);
    pym.v = ld4(p1, z, y > 0 ? y - 1 : 0, x0);
    pyp.v = ld4(p1, z, y < NY - 1 ? y + 1 : y, x0);
    pzm.v = ld4(p1, z > 0 ? z - 1 : 0, y, x0);
    pzp.v = ld4(p1, z < NZ - 1 ? z + 1 : z, y, x0);
    F4 rc, rym, ryp, rzm, rzp;
    rc.v  = ld4(rr, z, y, x0);
    rym.v = ld4(rr, z, y > 0 ? y - 1 : 0, x0);
    ryp.v = ld4(rr, z, y < NY - 1 ? y + 1 : y, x0);
    rzm.v = ld4(rr, z > 0 ? z - 1 : 0, y, x0);
    rzp.v = ld4(rr, z < NZ - 1 ? z + 1 : z, y, x0);
    float pxmS = tx ? p1[c - 1] : pc.f[0];
    float pxpS = (tx < 63) ? p1[c + 4] : pc.f[3];
    float rxmS = tx ? rr[c - 1] : rc.f[0];
    float rxpS = (tx < 63) ? rr[c + 4] : rc.f[3];

    F4 sc; sc.v = ld4(sg, z, y, x0);
    F4 a, b, cc;
    a.v = ld4(uIO, z, y, x0); b.v = ld4(vIO, z, y, x0); cc.v = ld4(wIO, z, y, x0);

    F4 ou, ov, ow, op, owm;
    #pragma unroll
    for (int i = 0; i < 4; i++) {
        float Dc  = cr[1 + (i >> 1)];
        float Dxm = (i == 0) ? cr[0] : cr[1 + ((i - 1) >> 1)];
        float Dxp = (i == 3) ? cr[3] : cr[1 + ((i + 1) >> 1)];
        float Dym = (i < 2) ? dym.x : dym.y;
        float Dyp = (i < 2) ? dyp.x : dyp.y;
        float Dzm = (i < 2) ? dzm.x : dzm.y;
        float Dzp = (i < 2) ? dzp.x : dzp.y;
        float pxm = i ? pc.f[i - 1] : pxmS, pxp = (i < 3) ? pc.f[i + 1] : pxpS;
        float rxm = i ? rc.f[i - 1] : rxmS, rxp = (i < 3) ? rc.f[i + 1] : rxpS;

        float p2c  = pc.f[i]  - Dc  + rc.f[i]  * SIXTH;
        float p2xm = pxm      - Dxm + rxm      * SIXTH;
        float p2xp = pxp      - Dxp + rxp      * SIXTH;
        float p2ym = pym.f[i] - Dym + rym.f[i] * SIXTH;
        float p2yp = pyp.f[i] - Dyp + ryp.f[i] * SIXTH;
        float p2zm = pzm.f[i] - Dzm + rzm.f[i] * SIXTH;
        float p2zp = pzp.f[i] - Dzp + rzp.f[i] * SIXTH;

        float dpx = 0.5f * (p2xp - p2xm);
        float dpy = 0.5f * (p2yp - p2ym);
        float dpz = 0.5f * (p2zp - p2zm);
        float inv = frcp(1.f + DT * sc.f[i]);
        ou.f[i]  = (a.f[i]  - dpx * DT) * inv;
        ov.f[i]  = (b.f[i]  - dpy * DT) * inv;
        ow.f[i]  = (cc.f[i] - dpz * DT) * inv;
        op.f[i]  = p2c;
        owm.f[i] = Dc;
    }
    st4(uIO, c, ou); st4(vIO, c, ov); st4(wIO, c, ow);
    st4(pout, c, op); st4(wmg, c, owm);
}

extern "C" void kernel_launch(void* const* d_in, const int* in_sizes, int n_in,
                              void* d_out, int out_size, void* d_ws, size_t ws_size,
                              hipStream_t stream) {
    const float* in_u  = (const float*)d_in[0];
    const float* in_v  = (const float*)d_in[1];
    const float* in_w  = (const float*)d_in[2];
    const float* in_p  = (const float*)d_in[3];
    const float* in_sg = (const float*)d_in[4];

    float* out   = (float*)d_out;
    float* O_u   = out;                      // u2 -> u_out
    float* O_v   = out + (size_t)NTOT;       // v2 -> v_out
    float* O_w   = out + (size_t)2 * NTOT;   // w2 -> w_out
    float* O_p   = out + (size_t)3 * NTOT;   // p2 (written once, by k_pfin)
    float* O_wmg = out + (size_t)4 * NTOT;   // r0 -> wmg
    float* O_r   = out + (size_t)5 * NTOT;   // final coarsest residual (512)

    float* ws  = (float*)d_ws;
    float* B0  = ws;                          // bu -> p1
    float* B1  = ws + (size_t)NTOT;           // bv -> r1res
    float* B2  = ws + (size_t)2 * NTOT;       // bw
    float* r1  = ws + (size_t)3 * NTOT;       // 262144
    float* r2  = r1 + 262144;                 // 32768
    float* r3  = r2 + 32768;                  // 4096
    float* r4w = r3 + 4096;                   // 512
    float* Dw  = r4w + 512;                   // 262144

    dim3 gF(2048);             dim3 bF(64, 4);
    dim3 gF2(1024);            dim3 bF2(64, 4, 2);
    dim3 gC(4, 4, 4);

    k_predict     <<<gF,  bF,  0, stream>>>(in_u, in_v, in_w, in_p, in_sg, B0, B1, B2);
    k_correct     <<<gF,  bF,  0, stream>>>(in_u, in_v, in_w, in_sg, B0, B1, B2, in_p,
                                            O_u, O_v, O_w);
    k_divresid_r  <<<gF2, bF2, 0, stream>>>(O_u, O_v, O_w, in_p, O_wmg /*r0*/, r1);

    // --- MG iteration 0 ---
    k_down        <<<gC, dim3(512), 0, stream>>>(r1, r2, r3, r4w);
    k_upf         <<<gC, dim3(512), 0, stream>>>(r4w, r3, r2, r1, Dw);
    k_pup_resid_r <<<gF2, bF2, 0, stream>>>(in_p, Dw, O_wmg, B0 /*p1*/, B1 /*r1res*/, r1);

    // --- MG iteration 1 ---
    k_down        <<<gC, dim3(512), 0, stream>>>(r1, r2, r3, O_r);
    k_upf         <<<gC, dim3(512), 0, stream>>>(O_r, r3, r2, r1, Dw);

    // fused p-update + projection + solid_body
    k_pfin        <<<gF, bF, 0, stream>>>(B0 /*p1*/, B1 /*r1res*/, Dw,
                                          O_u, O_v, O_w, in_sg, O_p, O_wmg);
}